// Round 1
// baseline (1098.064 us; speedup 1.0000x reference)
//
#include <hip/hip_runtime.h>
#include <stdint.h>

typedef __attribute__((ext_vector_type(8))) short s16x8;
typedef __attribute__((ext_vector_type(4))) float f32x4;

#define CB 2
#define CT 2048
#define CD 1024
#define CNH 16
#define CHD 64
#define CDFF 4096
#define CKB 512

__device__ __forceinline__ short f2bf(float f){
  union { float f; uint32_t u; } v; v.f = f;
  uint32_t r = v.u + 0x7FFFu + ((v.u >> 16) & 1u);
  return (short)(r >> 16);
}
__device__ __forceinline__ float bf2f(short h){
  union { uint32_t u; float f; } v; v.u = ((uint32_t)(uint16_t)h) << 16;
  return v.f;
}

#define GLOAD16(g, l) __builtin_amdgcn_global_load_lds( \
    (const __attribute__((address_space(1))) void*)(g), \
    (__attribute__((address_space(3))) void*)(l), 16, 0, 0)

// ---------------- gather + residual ----------------
__global__ void gather_kernel(const float* __restrict__ xp, const int* __restrict__ bnd,
                              const float* __restrict__ xr, float* __restrict__ x){
  int t = blockIdx.x, b = blockIdx.y, tid = threadIdx.x;
  int lo = 0, hi = CKB;
  while (lo < hi){ int mid = (lo + hi) >> 1; if (bnd[b*CKB + mid] <= t) lo = mid + 1; else hi = mid; }
  const float4* s  = (const float4*)(xp + ((size_t)b*CKB + lo)*CD);
  const float4* rr = (const float4*)(xr + ((size_t)b*CT + t)*CD);
  float4* dst      = (float4*)(x  + ((size_t)b*CT + t)*CD);
  float4 a = s[tid], c = rr[tid];
  float4 o; o.x = a.x + c.x; o.y = a.y + c.y; o.z = a.z + c.z; o.w = a.w + c.w;
  dst[tid] = o;
}

// ---------------- weight fp32 -> bf16 transpose ----------------
// W is (Kd x Nd) row-major fp32; dst[n*Kd + k] = bf16(W[k][n])
__global__ void wtrans_kernel(const float* __restrict__ W, short* __restrict__ dst,
                              int Kd, int Nd){
  __shared__ __align__(16) float tile[64*65];
  int n0 = blockIdx.x*64, k0 = blockIdx.y*64;
  #pragma unroll
  for (int i = 0; i < 16; ++i){
    int e = threadIdx.x + 256*i; int kl = e >> 6, nl = e & 63;
    tile[kl*65 + nl] = W[(size_t)(k0 + kl)*Nd + n0 + nl];
  }
  __syncthreads();
  #pragma unroll
  for (int i = 0; i < 16; ++i){
    int e = threadIdx.x + 256*i; int nl = e >> 6, kl = e & 63;
    dst[(size_t)(n0 + nl)*Kd + k0 + kl] = f2bf(tile[kl*65 + nl]);
  }
}

// ---------------- RMSNorm (one block per row, D=1024) ----------------
template<int OUT_BF16>
__global__ void rmsnorm_kernel(const float* __restrict__ x, const float* __restrict__ w,
                               void* __restrict__ outv){
  int row = blockIdx.x, tid = threadIdx.x;
  const float4 xv = ((const float4*)(x + (size_t)row*CD))[tid];
  float ss = xv.x*xv.x + xv.y*xv.y + xv.z*xv.z + xv.w*xv.w;
  #pragma unroll
  for (int m = 1; m < 64; m <<= 1) ss += __shfl_xor(ss, m);
  __shared__ float red[4];
  if ((tid & 63) == 0) red[tid >> 6] = ss;
  __syncthreads();
  float tot = red[0] + red[1] + red[2] + red[3];
  float scale = rsqrtf(tot * (1.0f/1024.0f) + 1e-5f);
  const float4 wv = ((const float4*)w)[tid];
  if (OUT_BF16){
    short4 o;
    o.x = f2bf(xv.x*scale*wv.x); o.y = f2bf(xv.y*scale*wv.y);
    o.z = f2bf(xv.z*scale*wv.z); o.w = f2bf(xv.w*scale*wv.w);
    ((short4*)outv)[(size_t)row*256 + tid] = o;
  } else {
    float4 o;
    o.x = xv.x*scale*wv.x; o.y = xv.y*scale*wv.y;
    o.z = xv.z*scale*wv.z; o.w = xv.w*scale*wv.w;
    ((float4*)outv)[(size_t)row*256 + tid] = o;
  }
}

// ---------------- GEMM: C[M,N] = A[M,K](bf16) * Bt[N,K](bf16)^T ----------------
// EPI 0: write bf16 C ; EPI 1: fp32 C += acc
template<int EPI>
__global__ __launch_bounds__(256) void gemm_bt(const short* __restrict__ A,
                                               const short* __restrict__ Bt,
                                               void* __restrict__ Cv,
                                               int M, int N, int K){
  __shared__ __align__(16) short sA[128*32];
  __shared__ __align__(16) short sB[128*32];
  const int tid = threadIdx.x;
  const int lane = tid & 63, wid = tid >> 6;
  const int wm = wid >> 1, wn = wid & 1;
  const int bm0 = blockIdx.y * 128, bn0 = blockIdx.x * 128;
  const int lr = lane & 15, lg = lane >> 4;
  f32x4 acc[4][4];
  #pragma unroll
  for (int i = 0; i < 4; ++i)
    #pragma unroll
    for (int j = 0; j < 4; ++j) acc[i][j] = (f32x4){0.f,0.f,0.f,0.f};

  const short* gA = A  + (size_t)(bm0 + wid*32 + (lane >> 2))*K + (lane & 3)*8;
  const short* gB = Bt + (size_t)(bn0 + wid*32 + (lane >> 2))*K + (lane & 3)*8;
  short* lA = sA + wid*32*32;
  short* lB = sB + wid*32*32;

  for (int k0 = 0; k0 < K; k0 += 32){
    #pragma unroll
    for (int iss = 0; iss < 2; ++iss){
      GLOAD16(gA + (size_t)iss*16*K + k0, lA + iss*16*32);
      GLOAD16(gB + (size_t)iss*16*K + k0, lB + iss*16*32);
    }
    __syncthreads();
    s16x8 af[4], bq[4];
    #pragma unroll
    for (int i = 0; i < 4; ++i) af[i] = *(const s16x8*)&sA[(wm*64 + i*16 + lr)*32 + lg*8];
    #pragma unroll
    for (int j = 0; j < 4; ++j) bq[j] = *(const s16x8*)&sB[(wn*64 + j*16 + lr)*32 + lg*8];
    #pragma unroll
    for (int i = 0; i < 4; ++i)
      #pragma unroll
      for (int j = 0; j < 4; ++j)
        acc[i][j] = __builtin_amdgcn_mfma_f32_16x16x32_bf16(af[i], bq[j], acc[i][j], 0, 0, 0);
    __syncthreads();
  }

  if (EPI == 0){
    short* C = (short*)Cv;
    #pragma unroll
    for (int i = 0; i < 4; ++i){
      int row0 = bm0 + wm*64 + i*16 + lg*4;
      #pragma unroll
      for (int j = 0; j < 4; ++j){
        int col = bn0 + wn*64 + j*16 + lr;
        #pragma unroll
        for (int r = 0; r < 4; ++r) C[(size_t)(row0 + r)*N + col] = f2bf(acc[i][j][r]);
      }
    }
  } else {
    float* C = (float*)Cv;
    #pragma unroll
    for (int i = 0; i < 4; ++i){
      int row0 = bm0 + wm*64 + i*16 + lg*4;
      #pragma unroll
      for (int j = 0; j < 4; ++j){
        int col = bn0 + wn*64 + j*16 + lr;
        #pragma unroll
        for (int r = 0; r < 4; ++r) C[(size_t)(row0 + r)*N + col] += acc[i][j][r];
      }
    }
  }
}

// ---------------- RoPE (q scaled by 1/sqrt(HD)), reads fused qkv ----------------
__global__ void rope_kernel(const short* __restrict__ qkv, const float* __restrict__ cosb,
                            const float* __restrict__ sinb, short* __restrict__ Qo,
                            short* __restrict__ Ko){
  int g = blockIdx.x*256 + threadIdx.x;    // B*T*NH*32 threads
  int d = g & 31;
  int h = (g >> 5) & 15;
  int t = (g >> 9) & 2047;
  int b = g >> 20;
  size_t row = (size_t)b*CT + t;
  const short* src = qkv + row*3072 + h*64;
  float q0 = bf2f(src[d]),        q1 = bf2f(src[d+32]);
  float k0 = bf2f(src[1024+d]),   k1 = bf2f(src[1024+d+32]);
  float c0 = cosb[t*64 + d], c1 = cosb[t*64 + d + 32];
  float s0 = sinb[t*64 + d], s1 = sinb[t*64 + d + 32];
  size_t o = row*CD + h*64;
  const float sc = 0.125f;  // 1/sqrt(64), folded into q
  Qo[o + d]      = f2bf((q0*c0 - q1*s0)*sc);
  Qo[o + d + 32] = f2bf((q1*c1 + q0*s1)*sc);
  Ko[o + d]      = f2bf(k0*c0 - k1*s0);
  Ko[o + d + 32] = f2bf(k1*c1 + k0*s1);
}

// ---------------- V transpose: qkv v-part -> Vt[b,h,d,t] ----------------
__global__ void vtrans_kernel(const short* __restrict__ qkv, short* __restrict__ Vt){
  __shared__ __align__(16) short tile[64*65];
  int t0 = blockIdx.x*64;
  int h = blockIdx.y & 15, b = blockIdx.y >> 4;
  #pragma unroll
  for (int i = 0; i < 16; ++i){
    int e = threadIdx.x + 256*i; int tl = e >> 6, d = e & 63;
    tile[tl*65 + d] = qkv[(size_t)(b*CT + t0 + tl)*3072 + 2048 + h*64 + d];
  }
  __syncthreads();
  #pragma unroll
  for (int i = 0; i < 16; ++i){
    int e = threadIdx.x + 256*i; int dl = e >> 6, tl = e & 63;
    Vt[((size_t)(b*CNH + h)*CHD + dl)*CT + t0 + tl] = tile[tl*65 + dl];
  }
}

// ---------------- causal flash attention ----------------
// Q,K: [b,t,h,d] bf16 (q pre-scaled); Vt: [b,h,d,t] bf16; O: [b,t,h,d] bf16
__global__ __launch_bounds__(256) void attn_kernel(const short* __restrict__ Q,
                                                   const short* __restrict__ Kb,
                                                   const short* __restrict__ Vt,
                                                   short* __restrict__ O){
  __shared__ __align__(16) short Kl[64*72];
  __shared__ __align__(16) short Vl[64*72];
  __shared__ __align__(16) short Pl[4][16*72];
  const int tid = threadIdx.x, lane = tid & 63, w = tid >> 6;
  const int qblk = blockIdx.x, h = blockIdx.y, b = blockIdx.z;
  const int lr = lane & 15, lg = lane >> 4;
  const int q0w = qblk*64 + w*16;

  s16x8 qf[2];
  {
    const short* qp = Q + ((size_t)(b*CT + q0w + lr)*CNH + h)*CHD + lg*8;
    qf[0] = *(const s16x8*)qp;
    qf[1] = *(const s16x8*)(qp + 32);
  }
  f32x4 oacc[4];
  #pragma unroll
  for (int dt = 0; dt < 4; ++dt) oacc[dt] = (f32x4){0.f,0.f,0.f,0.f};
  float m_r[4] = {-1e30f,-1e30f,-1e30f,-1e30f};
  float l_r[4] = {0.f,0.f,0.f,0.f};

  for (int j = 0; j <= qblk; ++j){
    const int kv0 = j*64;
    #pragma unroll
    for (int p = 0; p < 2; ++p){
      int c = tid + 256*p;
      int row = c >> 3, col8 = (c & 7)*8;
      *(s16x8*)&Kl[row*72 + col8] =
        *(const s16x8*)&Kb[((size_t)(b*CT + kv0 + row)*CNH + h)*CHD + col8];
      *(s16x8*)&Vl[row*72 + col8] =
        *(const s16x8*)&Vt[((size_t)(b*CNH + h)*CHD + row)*CT + kv0 + col8];
    }
    __syncthreads();

    f32x4 sc[4];
    #pragma unroll
    for (int nt = 0; nt < 4; ++nt){
      s16x8 b0 = *(const s16x8*)&Kl[(nt*16 + lr)*72 + lg*8];
      s16x8 b1 = *(const s16x8*)&Kl[(nt*16 + lr)*72 + 32 + lg*8];
      f32x4 z = (f32x4){0.f,0.f,0.f,0.f};
      z = __builtin_amdgcn_mfma_f32_16x16x32_bf16(qf[0], b0, z, 0, 0, 0);
      z = __builtin_amdgcn_mfma_f32_16x16x32_bf16(qf[1], b1, z, 0, 0, 0);
      sc[nt] = z;
    }
    if (j == qblk){
      #pragma unroll
      for (int nt = 0; nt < 4; ++nt)
        #pragma unroll
        for (int r = 0; r < 4; ++r)
          if (kv0 + nt*16 + lr > q0w + lg*4 + r) sc[nt][r] = -1e30f;
    }
    float mx[4];
    #pragma unroll
    for (int r = 0; r < 4; ++r)
      mx[r] = fmaxf(fmaxf(sc[0][r], sc[1][r]), fmaxf(sc[2][r], sc[3][r]));
    #pragma unroll
    for (int msk = 1; msk < 16; msk <<= 1)
      #pragma unroll
      for (int r = 0; r < 4; ++r) mx[r] = fmaxf(mx[r], __shfl_xor(mx[r], msk));
    float corr[4], rs[4];
    #pragma unroll
    for (int r = 0; r < 4; ++r){
      float mn = fmaxf(m_r[r], mx[r]);
      corr[r] = __expf(m_r[r] - mn);
      m_r[r] = mn; rs[r] = 0.f;
    }
    #pragma unroll
    for (int nt = 0; nt < 4; ++nt)
      #pragma unroll
      for (int r = 0; r < 4; ++r){
        float pv = __expf(sc[nt][r] - m_r[r]);
        sc[nt][r] = pv; rs[r] += pv;
      }
    #pragma unroll
    for (int msk = 1; msk < 16; msk <<= 1)
      #pragma unroll
      for (int r = 0; r < 4; ++r) rs[r] += __shfl_xor(rs[r], msk);
    #pragma unroll
    for (int r = 0; r < 4; ++r) l_r[r] = l_r[r]*corr[r] + rs[r];
    #pragma unroll
    for (int dt = 0; dt < 4; ++dt)
      #pragma unroll
      for (int r = 0; r < 4; ++r) oacc[dt][r] *= corr[r];
    #pragma unroll
    for (int nt = 0; nt < 4; ++nt)
      #pragma unroll
      for (int r = 0; r < 4; ++r)
        Pl[w][(lg*4 + r)*72 + nt*16 + lr] = f2bf(sc[nt][r]);
    #pragma unroll
    for (int kc = 0; kc < 2; ++kc){
      s16x8 pa = *(const s16x8*)&Pl[w][lr*72 + kc*32 + lg*8];
      #pragma unroll
      for (int dt = 0; dt < 4; ++dt){
        s16x8 bv = *(const s16x8*)&Vl[(dt*16 + lr)*72 + kc*32 + lg*8];
        oacc[dt] = __builtin_amdgcn_mfma_f32_16x16x32_bf16(pa, bv, oacc[dt], 0, 0, 0);
      }
    }
    __syncthreads();
  }
  #pragma unroll
  for (int dt = 0; dt < 4; ++dt)
    #pragma unroll
    for (int r = 0; r < 4; ++r)
      O[((size_t)(b*CT + q0w + lg*4 + r)*CNH + h)*CHD + dt*16 + lr] =
        f2bf(oacc[dt][r] / l_r[r]);
}

// ---------------- SiLU(u) * g, bf16 in/out ----------------
__global__ void silu_kernel(const short* __restrict__ ug, short* __restrict__ m){
  int g = blockIdx.x*256 + threadIdx.x;   // 4 outputs/thread
  int col4 = g & 1023; int row = g >> 10;
  short4 u  = *(const short4*)&ug[(size_t)row*8192 + col4*4];
  short4 gg = *(const short4*)&ug[(size_t)row*8192 + 4096 + col4*4];
  short4 o;
  {
    float a = bf2f(u.x), bb = bf2f(gg.x); o.x = f2bf(a / (1.f + __expf(-a)) * bb);
    a = bf2f(u.y); bb = bf2f(gg.y); o.y = f2bf(a / (1.f + __expf(-a)) * bb);
    a = bf2f(u.z); bb = bf2f(gg.z); o.z = f2bf(a / (1.f + __expf(-a)) * bb);
    a = bf2f(u.w); bb = bf2f(gg.w); o.w = f2bf(a / (1.f + __expf(-a)) * bb);
  }
  *(short4*)&m[(size_t)row*4096 + col4*4] = o;
}

// ---------------- launch ----------------
extern "C" void kernel_launch(void* const* d_in, const int* in_sizes, int n_in,
                              void* d_out, int out_size, void* d_ws, size_t ws_size,
                              hipStream_t stream){
  (void)in_sizes; (void)n_in; (void)out_size; (void)ws_size;
  const float* x_processed = (const float*)d_in[0];
  const int*   boundaries  = (const int*)d_in[1];
  const float* x_residual  = (const float*)d_in[3];
  const float* cosb        = (const float*)d_in[4];
  const float* sinb        = (const float*)d_in[5];
  const float* wq          = (const float*)d_in[7];
  const float* wk          = (const float*)d_in[8];
  const float* wv          = (const float*)d_in[9];
  const float* wo          = (const float*)d_in[10];
  const float* attn_nw     = (const float*)d_in[11];
  const float* mlp_nw      = (const float*)d_in[12];
  const float* w1          = (const float*)d_in[13];
  const float* w3          = (const float*)d_in[14];
  const float* w2          = (const float*)d_in[15];
  const float* final_nw    = (const float*)d_in[16];

  char* p = (char*)d_ws;
  auto alloc = [&](size_t bytes)->char*{
    char* r = p; p += (bytes + 255) & ~(size_t)255; return r;
  };
  short* wqkvT = (short*)alloc((size_t)2*3072*1024*2);
  short* woT   = (short*)alloc((size_t)2*1024*1024*2);
  short* w13T  = (short*)alloc((size_t)2*8192*1024*2);
  short* w2T   = (short*)alloc((size_t)2*1024*4096*2);
  float* x     = (float*)alloc((size_t)4096*1024*4);
  short* hbuf  = (short*)alloc((size_t)4096*1024*2);
  short* qkv   = (short*)alloc((size_t)4096*3072*2);
  short* qr    = (short*)alloc((size_t)4096*1024*2);
  short* kr    = (short*)alloc((size_t)4096*1024*2);
  short* vt    = (short*)alloc((size_t)4096*1024*2);
  short* obuf  = (short*)alloc((size_t)4096*1024*2);
  short* ug    = (short*)alloc((size_t)4096*8192*2);
  short* mbuf  = (short*)alloc((size_t)4096*4096*2);

  for (int l = 0; l < 2; ++l){
    size_t wOff = (size_t)l*1024*1024;
    wtrans_kernel<<<dim3(16,16),256,0,stream>>>(wq + wOff, wqkvT + (size_t)l*3072*1024,                     1024, 1024);
    wtrans_kernel<<<dim3(16,16),256,0,stream>>>(wk + wOff, wqkvT + (size_t)l*3072*1024 + (size_t)1024*1024, 1024, 1024);
    wtrans_kernel<<<dim3(16,16),256,0,stream>>>(wv + wOff, wqkvT + (size_t)l*3072*1024 + (size_t)2048*1024, 1024, 1024);
    wtrans_kernel<<<dim3(16,16),256,0,stream>>>(wo + wOff, woT + (size_t)l*1024*1024,                       1024, 1024);
    wtrans_kernel<<<dim3(64,16),256,0,stream>>>(w1 + (size_t)l*1024*4096, w13T + (size_t)l*8192*1024,                     1024, 4096);
    wtrans_kernel<<<dim3(64,16),256,0,stream>>>(w3 + (size_t)l*1024*4096, w13T + (size_t)l*8192*1024 + (size_t)4096*1024, 1024, 4096);
    wtrans_kernel<<<dim3(16,64),256,0,stream>>>(w2 + (size_t)l*4096*1024, w2T + (size_t)l*1024*4096,                      4096, 1024);
  }
  gather_kernel<<<dim3(2048,2),256,0,stream>>>(x_processed, boundaries, x_residual, x);
  for (int l = 0; l < 2; ++l){
    rmsnorm_kernel<1><<<4096,256,0,stream>>>(x, attn_nw + l*1024, hbuf);
    gemm_bt<0><<<dim3(24,32),256,0,stream>>>(hbuf, wqkvT + (size_t)l*3072*1024, qkv, 4096, 3072, 1024);
    rope_kernel<<<8192,256,0,stream>>>(qkv, cosb, sinb, qr, kr);
    vtrans_kernel<<<dim3(32,32),256,0,stream>>>(qkv, vt);
    attn_kernel<<<dim3(32,16,2),256,0,stream>>>(qr, kr, vt, obuf);
    gemm_bt<1><<<dim3(8,32),256,0,stream>>>(obuf, woT + (size_t)l*1024*1024, x, 4096, 1024, 1024);
    rmsnorm_kernel<1><<<4096,256,0,stream>>>(x, mlp_nw + l*1024, hbuf);
    gemm_bt<0><<<dim3(64,32),256,0,stream>>>(hbuf, w13T + (size_t)l*8192*1024, ug, 4096, 8192, 1024);
    silu_kernel<<<16384,256,0,stream>>>(ug, mbuf);
    gemm_bt<1><<<dim3(8,32),256,0,stream>>>(mbuf, w2T + (size_t)l*1024*4096, x, 4096, 1024, 4096);
  }
  rmsnorm_kernel<0><<<4096,256,0,stream>>>(x, final_nw, d_out);
}

// Round 2
// 927.890 us; speedup vs baseline: 1.1834x; 1.1834x over previous
//
#include <hip/hip_runtime.h>
#include <stdint.h>

typedef __attribute__((ext_vector_type(8))) short s16x8;
typedef __attribute__((ext_vector_type(4))) float f32x4;

#define CB 2
#define CT 2048
#define CD 1024
#define CNH 16
#define CHD 64
#define CDFF 4096
#define CKB 512

__device__ __forceinline__ short f2bf(float f){
  union { float f; uint32_t u; } v; v.f = f;
  uint32_t r = v.u + 0x7FFFu + ((v.u >> 16) & 1u);
  return (short)(r >> 16);
}
__device__ __forceinline__ float bf2f(short h){
  union { uint32_t u; float f; } v; v.u = ((uint32_t)(uint16_t)h) << 16;
  return v.f;
}

#define GLOAD16(g, l) __builtin_amdgcn_global_load_lds( \
    (const __attribute__((address_space(1))) void*)(g), \
    (__attribute__((address_space(3))) void*)(l), 16, 0, 0)

// ---------------- gather + residual ----------------
__global__ void gather_kernel(const float* __restrict__ xp, const int* __restrict__ bnd,
                              const float* __restrict__ xr, float* __restrict__ x){
  int t = blockIdx.x, b = blockIdx.y, tid = threadIdx.x;
  int lo = 0, hi = CKB;
  while (lo < hi){ int mid = (lo + hi) >> 1; if (bnd[b*CKB + mid] <= t) lo = mid + 1; else hi = mid; }
  const float4* s  = (const float4*)(xp + ((size_t)b*CKB + lo)*CD);
  const float4* rr = (const float4*)(xr + ((size_t)b*CT + t)*CD);
  float4* dst      = (float4*)(x  + ((size_t)b*CT + t)*CD);
  float4 a = s[tid], c = rr[tid];
  float4 o; o.x = a.x + c.x; o.y = a.y + c.y; o.z = a.z + c.z; o.w = a.w + c.w;
  dst[tid] = o;
}

// ---------------- weight fp32 -> bf16 transpose ----------------
__global__ void wtrans_kernel(const float* __restrict__ W, short* __restrict__ dst,
                              int Kd, int Nd){
  __shared__ __align__(16) float tile[64*65];
  int n0 = blockIdx.x*64, k0 = blockIdx.y*64;
  #pragma unroll
  for (int i = 0; i < 16; ++i){
    int e = threadIdx.x + 256*i; int kl = e >> 6, nl = e & 63;
    tile[kl*65 + nl] = W[(size_t)(k0 + kl)*Nd + n0 + nl];
  }
  __syncthreads();
  #pragma unroll
  for (int i = 0; i < 16; ++i){
    int e = threadIdx.x + 256*i; int nl = e >> 6, kl = e & 63;
    dst[(size_t)(n0 + nl)*Kd + k0 + kl] = f2bf(tile[kl*65 + nl]);
  }
}

// ---------------- RMSNorm ----------------
template<int OUT_BF16>
__global__ void rmsnorm_kernel(const float* __restrict__ x, const float* __restrict__ w,
                               void* __restrict__ outv){
  int row = blockIdx.x, tid = threadIdx.x;
  const float4 xv = ((const float4*)(x + (size_t)row*CD))[tid];
  float ss = xv.x*xv.x + xv.y*xv.y + xv.z*xv.z + xv.w*xv.w;
  #pragma unroll
  for (int m = 1; m < 64; m <<= 1) ss += __shfl_xor(ss, m);
  __shared__ float red[4];
  if ((tid & 63) == 0) red[tid >> 6] = ss;
  __syncthreads();
  float tot = red[0] + red[1] + red[2] + red[3];
  float scale = rsqrtf(tot * (1.0f/1024.0f) + 1e-5f);
  const float4 wv = ((const float4*)w)[tid];
  if (OUT_BF16){
    short4 o;
    o.x = f2bf(xv.x*scale*wv.x); o.y = f2bf(xv.y*scale*wv.y);
    o.z = f2bf(xv.z*scale*wv.z); o.w = f2bf(xv.w*scale*wv.w);
    ((short4*)outv)[(size_t)row*256 + tid] = o;
  } else {
    float4 o;
    o.x = xv.x*scale*wv.x; o.y = xv.y*scale*wv.y;
    o.z = xv.z*scale*wv.z; o.w = xv.w*scale*wv.w;
    ((float4*)outv)[(size_t)row*256 + tid] = o;
  }
}

// ---------------- GEMM: C[M,N] = A[M,K](bf16) * Bt[N,K](bf16)^T ----------------
template<int EPI>
__global__ __launch_bounds__(256) void gemm_bt(const short* __restrict__ A,
                                               const short* __restrict__ Bt,
                                               void* __restrict__ Cv,
                                               int M, int N, int K){
  __shared__ __align__(16) short sA[128*32];
  __shared__ __align__(16) short sB[128*32];
  const int tid = threadIdx.x;
  const int lane = tid & 63, wid = tid >> 6;
  const int wm = wid >> 1, wn = wid & 1;
  const int bm0 = blockIdx.y * 128, bn0 = blockIdx.x * 128;
  const int lr = lane & 15, lg = lane >> 4;
  f32x4 acc[4][4];
  #pragma unroll
  for (int i = 0; i < 4; ++i)
    #pragma unroll
    for (int j = 0; j < 4; ++j) acc[i][j] = (f32x4){0.f,0.f,0.f,0.f};

  const short* gA = A  + (size_t)(bm0 + wid*32 + (lane >> 2))*K + (lane & 3)*8;
  const short* gB = Bt + (size_t)(bn0 + wid*32 + (lane >> 2))*K + (lane & 3)*8;
  short* lA = sA + wid*32*32;
  short* lB = sB + wid*32*32;

  for (int k0 = 0; k0 < K; k0 += 32){
    #pragma unroll
    for (int iss = 0; iss < 2; ++iss){
      GLOAD16(gA + (size_t)iss*16*K + k0, lA + iss*16*32);
      GLOAD16(gB + (size_t)iss*16*K + k0, lB + iss*16*32);
    }
    __syncthreads();
    s16x8 af[4], bq[4];
    #pragma unroll
    for (int i = 0; i < 4; ++i) af[i] = *(const s16x8*)&sA[(wm*64 + i*16 + lr)*32 + lg*8];
    #pragma unroll
    for (int j = 0; j < 4; ++j) bq[j] = *(const s16x8*)&sB[(wn*64 + j*16 + lr)*32 + lg*8];
    #pragma unroll
    for (int i = 0; i < 4; ++i)
      #pragma unroll
      for (int j = 0; j < 4; ++j)
        acc[i][j] = __builtin_amdgcn_mfma_f32_16x16x32_bf16(af[i], bq[j], acc[i][j], 0, 0, 0);
    __syncthreads();
  }

  if (EPI == 0){
    short* C = (short*)Cv;
    #pragma unroll
    for (int i = 0; i < 4; ++i){
      int row0 = bm0 + wm*64 + i*16 + lg*4;
      #pragma unroll
      for (int j = 0; j < 4; ++j){
        int col = bn0 + wn*64 + j*16 + lr;
        #pragma unroll
        for (int r = 0; r < 4; ++r) C[(size_t)(row0 + r)*N + col] = f2bf(acc[i][j][r]);
      }
    }
  } else {
    float* C = (float*)Cv;
    #pragma unroll
    for (int i = 0; i < 4; ++i){
      int row0 = bm0 + wm*64 + i*16 + lg*4;
      #pragma unroll
      for (int j = 0; j < 4; ++j){
        int col = bn0 + wn*64 + j*16 + lr;
        #pragma unroll
        for (int r = 0; r < 4; ++r) C[(size_t)(row0 + r)*N + col] += acc[i][j][r];
      }
    }
  }
}

// ---------------- RoPE ----------------
__global__ void rope_kernel(const short* __restrict__ qkv, const float* __restrict__ cosb,
                            const float* __restrict__ sinb, short* __restrict__ Qo,
                            short* __restrict__ Ko){
  int g = blockIdx.x*256 + threadIdx.x;
  int d = g & 31;
  int h = (g >> 5) & 15;
  int t = (g >> 9) & 2047;
  int b = g >> 20;
  size_t row = (size_t)b*CT + t;
  const short* src = qkv + row*3072 + h*64;
  float q0 = bf2f(src[d]),        q1 = bf2f(src[d+32]);
  float k0 = bf2f(src[1024+d]),   k1 = bf2f(src[1024+d+32]);
  float c0 = cosb[t*64 + d], c1 = cosb[t*64 + d + 32];
  float s0 = sinb[t*64 + d], s1 = sinb[t*64 + d + 32];
  size_t o = row*CD + h*64;
  const float sc = 0.125f;
  Qo[o + d]      = f2bf((q0*c0 - q1*s0)*sc);
  Qo[o + d + 32] = f2bf((q1*c1 + q0*s1)*sc);
  Ko[o + d]      = f2bf(k0*c0 - k1*s0);
  Ko[o + d + 32] = f2bf(k1*c1 + k0*s1);
}

// ---------------- V transpose ----------------
__global__ void vtrans_kernel(const short* __restrict__ qkv, short* __restrict__ Vt){
  __shared__ __align__(16) short tile[64*65];
  int t0 = blockIdx.x*64;
  int h = blockIdx.y & 15, b = blockIdx.y >> 4;
  #pragma unroll
  for (int i = 0; i < 16; ++i){
    int e = threadIdx.x + 256*i; int tl = e >> 6, d = e & 63;
    tile[tl*65 + d] = qkv[(size_t)(b*CT + t0 + tl)*3072 + 2048 + h*64 + d];
  }
  __syncthreads();
  #pragma unroll
  for (int i = 0; i < 16; ++i){
    int e = threadIdx.x + 256*i; int dl = e >> 6, tl = e & 63;
    Vt[((size_t)(b*CNH + h)*CHD + dl)*CT + t0 + tl] = tile[tl*65 + dl];
  }
}

// ---------------- causal flash attention v2 ----------------
// QBLK=128 (32 q-rows/wave), swapped QK^T, register prefetch of K/V tiles.
// Q,K: [b,t,h,d] bf16 (q pre-scaled); Vt: [b,h,d,t] bf16; O: [b,t,h,d] bf16
__global__ __launch_bounds__(256) void attn_kernel(const short* __restrict__ Q,
                                                   const short* __restrict__ Kb,
                                                   const short* __restrict__ Vt,
                                                   short* __restrict__ O){
  __shared__ __align__(16) short Kl[64*72];
  __shared__ __align__(16) short Vl[64*72];
  __shared__ __align__(16) short Pl[4][32*72];
  const int tid = threadIdx.x, lane = tid & 63, w = tid >> 6;
  const int qblk = gridDim.x - 1 - blockIdx.x;   // longest blocks first
  const int h = blockIdx.y, b = blockIdx.z;
  const int lr = lane & 15, lg = lane >> 4;
  const int wq0 = qblk*128 + w*32;

  // Q fragments (used as MFMA B-operand in swapped QK^T): qf[qh][kc]
  s16x8 qf[2][2];
  #pragma unroll
  for (int qh = 0; qh < 2; ++qh){
    const short* qp = Q + ((size_t)(b*CT + wq0 + qh*16 + lr)*CNH + h)*CHD + lg*8;
    qf[qh][0] = *(const s16x8*)qp;
    qf[qh][1] = *(const s16x8*)(qp + 32);
  }
  f32x4 oacc[2][4];
  #pragma unroll
  for (int qh = 0; qh < 2; ++qh)
    #pragma unroll
    for (int dt = 0; dt < 4; ++dt) oacc[qh][dt] = (f32x4){0.f,0.f,0.f,0.f};
  float m_r[2] = {-1e30f,-1e30f};
  float l_r[2] = {0.f,0.f};

  const int jmax = 2*qblk + 2;
  // staging geometry: 256 threads x 2 chunks x 8 shorts = 64x64 tile
  const short* gK = Kb + (size_t)b*CT*CD + h*CHD;     // + (kv+row)*CD + col8
  const short* gV = Vt + (size_t)(b*CNH + h)*CHD*CT;  // + row*CT + kv + col8
  const int srow0 = tid >> 3, scol = (tid & 7)*8;     // p adds 32 rows

  // prologue: stage tile 0
  {
    #pragma unroll
    for (int p = 0; p < 2; ++p){
      int row = srow0 + p*32;
      s16x8 k0 = *(const s16x8*)(gK + (size_t)row*CD + scol);
      s16x8 v0 = *(const s16x8*)(gV + (size_t)row*CT + scol);
      *(s16x8*)&Kl[row*72 + scol] = k0;
      *(s16x8*)&Vl[row*72 + scol] = v0;
    }
  }
  __syncthreads();

  for (int j = 0; j < jmax; ++j){
    const int kv0 = j*64;
    // issue prefetch of tile j+1 into registers (latency hides under compute)
    s16x8 nk[2], nv[2];
    const bool havenext = (j + 1 < jmax);
    if (havenext){
      const int kv1 = kv0 + 64;
      #pragma unroll
      for (int p = 0; p < 2; ++p){
        int row = srow0 + p*32;
        nk[p] = *(const s16x8*)(gK + (size_t)(kv1 + row)*CD + scol);
        nv[p] = *(const s16x8*)(gV + (size_t)row*CT + kv1 + scol);
      }
    }

    if (kv0 < wq0 + 32){   // wave-uniform: tile not fully masked for this wave
      // QK^T (swapped): sc[qh][nt], lane holds k = nt*16+lg*4+r, q = lr
      f32x4 sc[2][4];
      #pragma unroll
      for (int nt = 0; nt < 4; ++nt){
        s16x8 k0 = *(const s16x8*)&Kl[(nt*16 + lr)*72 + lg*8];
        s16x8 k1 = *(const s16x8*)&Kl[(nt*16 + lr)*72 + 32 + lg*8];
        #pragma unroll
        for (int qh = 0; qh < 2; ++qh){
          f32x4 z = (f32x4){0.f,0.f,0.f,0.f};
          z = __builtin_amdgcn_mfma_f32_16x16x32_bf16(k0, qf[qh][0], z, 0, 0, 0);
          z = __builtin_amdgcn_mfma_f32_16x16x32_bf16(k1, qf[qh][1], z, 0, 0, 0);
          sc[qh][nt] = z;
        }
      }
      if (kv0 + 64 > wq0){  // diagonal region: apply causal mask
        #pragma unroll
        for (int qh = 0; qh < 2; ++qh)
          #pragma unroll
          for (int nt = 0; nt < 4; ++nt)
            #pragma unroll
            for (int r = 0; r < 4; ++r)
              if (kv0 + nt*16 + lg*4 + r > wq0 + qh*16 + lr) sc[qh][nt][r] = -1e30f;
      }
      // online softmax: per-lane 16 k-values, cross-lane over lg only (2 steps)
      #pragma unroll
      for (int qh = 0; qh < 2; ++qh){
        float mx = sc[qh][0][0];
        #pragma unroll
        for (int nt = 0; nt < 4; ++nt)
          #pragma unroll
          for (int r = 0; r < 4; ++r) mx = fmaxf(mx, sc[qh][nt][r]);
        mx = fmaxf(mx, __shfl_xor(mx, 16));
        mx = fmaxf(mx, __shfl_xor(mx, 32));
        float mn = fmaxf(m_r[qh], mx);
        float corr = __expf(m_r[qh] - mn);
        m_r[qh] = mn;
        float rs = 0.f;
        #pragma unroll
        for (int nt = 0; nt < 4; ++nt)
          #pragma unroll
          for (int r = 0; r < 4; ++r){
            float pv = __expf(sc[qh][nt][r] - mn);
            rs += pv;
            Pl[w][(qh*16 + lr)*72 + nt*16 + lg*4 + r] = f2bf(pv);
          }
        rs += __shfl_xor(rs, 16);
        rs += __shfl_xor(rs, 32);
        l_r[qh] = l_r[qh]*corr + rs;
        // rescale oacc: need corr at q = lg*4 + r
        #pragma unroll
        for (int r = 0; r < 4; ++r){
          float c4 = __shfl(corr, lg*4 + r);
          #pragma unroll
          for (int dt = 0; dt < 4; ++dt) oacc[qh][dt][r] *= c4;
        }
      }
      // PV: A = P rows (q), B = Vl rows (d)
      s16x8 pa[2][2];
      #pragma unroll
      for (int qh = 0; qh < 2; ++qh){
        pa[qh][0] = *(const s16x8*)&Pl[w][(qh*16 + lr)*72 + lg*8];
        pa[qh][1] = *(const s16x8*)&Pl[w][(qh*16 + lr)*72 + 32 + lg*8];
      }
      #pragma unroll
      for (int dt = 0; dt < 4; ++dt){
        s16x8 v0 = *(const s16x8*)&Vl[(dt*16 + lr)*72 + lg*8];
        s16x8 v1 = *(const s16x8*)&Vl[(dt*16 + lr)*72 + 32 + lg*8];
        #pragma unroll
        for (int qh = 0; qh < 2; ++qh){
          oacc[qh][dt] = __builtin_amdgcn_mfma_f32_16x16x32_bf16(pa[qh][0], v0, oacc[qh][dt], 0, 0, 0);
          oacc[qh][dt] = __builtin_amdgcn_mfma_f32_16x16x32_bf16(pa[qh][1], v1, oacc[qh][dt], 0, 0, 0);
        }
      }
    }
    __syncthreads();   // all waves done reading Kl/Vl
    if (havenext){
      #pragma unroll
      for (int p = 0; p < 2; ++p){
        int row = srow0 + p*32;
        *(s16x8*)&Kl[row*72 + scol] = nk[p];
        *(s16x8*)&Vl[row*72 + scol] = nv[p];
      }
    }
    __syncthreads();   // writes visible before next compute
  }

  #pragma unroll
  for (int qh = 0; qh < 2; ++qh)
    #pragma unroll
    for (int r = 0; r < 4; ++r){
      float lf = __shfl(l_r[qh], lg*4 + r);
      float inv = 1.f / lf;
      int qrow = wq0 + qh*16 + lg*4 + r;
      #pragma unroll
      for (int dt = 0; dt < 4; ++dt)
        O[((size_t)(b*CT + qrow)*CNH + h)*CHD + dt*16 + lr] = f2bf(oacc[qh][dt][r] * inv);
    }
}

// ---------------- SiLU(u) * g ----------------
__global__ void silu_kernel(const short* __restrict__ ug, short* __restrict__ m){
  int g = blockIdx.x*256 + threadIdx.x;
  int col4 = g & 1023; int row = g >> 10;
  short4 u  = *(const short4*)&ug[(size_t)row*8192 + col4*4];
  short4 gg = *(const short4*)&ug[(size_t)row*8192 + 4096 + col4*4];
  short4 o;
  {
    float a = bf2f(u.x), bb = bf2f(gg.x); o.x = f2bf(a / (1.f + __expf(-a)) * bb);
    a = bf2f(u.y); bb = bf2f(gg.y); o.y = f2bf(a / (1.f + __expf(-a)) * bb);
    a = bf2f(u.z); bb = bf2f(gg.z); o.z = f2bf(a / (1.f + __expf(-a)) * bb);
    a = bf2f(u.w); bb = bf2f(gg.w); o.w = f2bf(a / (1.f + __expf(-a)) * bb);
  }
  *(short4*)&m[(size_t)row*4096 + col4*4] = o;
}

// ---------------- launch ----------------
extern "C" void kernel_launch(void* const* d_in, const int* in_sizes, int n_in,
                              void* d_out, int out_size, void* d_ws, size_t ws_size,
                              hipStream_t stream){
  (void)in_sizes; (void)n_in; (void)out_size; (void)ws_size;
  const float* x_processed = (const float*)d_in[0];
  const int*   boundaries  = (const int*)d_in[1];
  const float* x_residual  = (const float*)d_in[3];
  const float* cosb        = (const float*)d_in[4];
  const float* sinb        = (const float*)d_in[5];
  const float* wq          = (const float*)d_in[7];
  const float* wk          = (const float*)d_in[8];
  const float* wv          = (const float*)d_in[9];
  const float* wo          = (const float*)d_in[10];
  const float* attn_nw     = (const float*)d_in[11];
  const float* mlp_nw      = (const float*)d_in[12];
  const float* w1          = (const float*)d_in[13];
  const float* w3          = (const float*)d_in[14];
  const float* w2          = (const float*)d_in[15];
  const float* final_nw    = (const float*)d_in[16];

  char* p = (char*)d_ws;
  auto alloc = [&](size_t bytes)->char*{
    char* r = p; p += (bytes + 255) & ~(size_t)255; return r;
  };
  short* wqkvT = (short*)alloc((size_t)2*3072*1024*2);
  short* woT   = (short*)alloc((size_t)2*1024*1024*2);
  short* w13T  = (short*)alloc((size_t)2*8192*1024*2);
  short* w2T   = (short*)alloc((size_t)2*1024*4096*2);
  float* x     = (float*)alloc((size_t)4096*1024*4);
  short* hbuf  = (short*)alloc((size_t)4096*1024*2);
  short* qkv   = (short*)alloc((size_t)4096*3072*2);
  short* qr    = (short*)alloc((size_t)4096*1024*2);
  short* kr    = (short*)alloc((size_t)4096*1024*2);
  short* vt    = (short*)alloc((size_t)4096*1024*2);
  short* obuf  = (short*)alloc((size_t)4096*1024*2);
  short* ug    = (short*)alloc((size_t)4096*8192*2);
  short* mbuf  = (short*)alloc((size_t)4096*4096*2);

  for (int l = 0; l < 2; ++l){
    size_t wOff = (size_t)l*1024*1024;
    wtrans_kernel<<<dim3(16,16),256,0,stream>>>(wq + wOff, wqkvT + (size_t)l*3072*1024,                     1024, 1024);
    wtrans_kernel<<<dim3(16,16),256,0,stream>>>(wk + wOff, wqkvT + (size_t)l*3072*1024 + (size_t)1024*1024, 1024, 1024);
    wtrans_kernel<<<dim3(16,16),256,0,stream>>>(wv + wOff, wqkvT + (size_t)l*3072*1024 + (size_t)2048*1024, 1024, 1024);
    wtrans_kernel<<<dim3(16,16),256,0,stream>>>(wo + wOff, woT + (size_t)l*1024*1024,                       1024, 1024);
    wtrans_kernel<<<dim3(64,16),256,0,stream>>>(w1 + (size_t)l*1024*4096, w13T + (size_t)l*8192*1024,                     1024, 4096);
    wtrans_kernel<<<dim3(64,16),256,0,stream>>>(w3 + (size_t)l*1024*4096, w13T + (size_t)l*8192*1024 + (size_t)4096*1024, 1024, 4096);
    wtrans_kernel<<<dim3(16,64),256,0,stream>>>(w2 + (size_t)l*4096*1024, w2T + (size_t)l*1024*4096,                      4096, 1024);
  }
  gather_kernel<<<dim3(2048,2),256,0,stream>>>(x_processed, boundaries, x_residual, x);
  for (int l = 0; l < 2; ++l){
    rmsnorm_kernel<1><<<4096,256,0,stream>>>(x, attn_nw + l*1024, hbuf);
    gemm_bt<0><<<dim3(24,32),256,0,stream>>>(hbuf, wqkvT + (size_t)l*3072*1024, qkv, 4096, 3072, 1024);
    rope_kernel<<<8192,256,0,stream>>>(qkv, cosb, sinb, qr, kr);
    vtrans_kernel<<<dim3(32,32),256,0,stream>>>(qkv, vt);
    attn_kernel<<<dim3(16,16,2),256,0,stream>>>(qr, kr, vt, obuf);
    gemm_bt<1><<<dim3(8,32),256,0,stream>>>(obuf, woT + (size_t)l*1024*1024, x, 4096, 1024, 1024);
    rmsnorm_kernel<1><<<4096,256,0,stream>>>(x, mlp_nw + l*1024, hbuf);
    gemm_bt<0><<<dim3(64,32),256,0,stream>>>(hbuf, w13T + (size_t)l*8192*1024, ug, 4096, 8192, 1024);
    silu_kernel<<<16384,256,0,stream>>>(ug, mbuf);
    gemm_bt<1><<<dim3(8,32),256,0,stream>>>(mbuf, w2T + (size_t)l*1024*4096, x, 4096, 1024, 4096);
  }
  rmsnorm_kernel<0><<<4096,256,0,stream>>>(x, final_nw, d_out);
}

// Round 3
// 811.251 us; speedup vs baseline: 1.3535x; 1.1438x over previous
//
#include <hip/hip_runtime.h>
#include <stdint.h>

typedef __attribute__((ext_vector_type(8))) short s16x8;
typedef __attribute__((ext_vector_type(4))) float f32x4;

#define CB 2
#define CT 2048
#define CD 1024
#define CNH 16
#define CHD 64
#define CDFF 4096
#define CKB 512

__device__ __forceinline__ short f2bf(float f){
  union { float f; uint32_t u; } v; v.f = f;
  uint32_t r = v.u + 0x7FFFu + ((v.u >> 16) & 1u);
  return (short)(r >> 16);
}
__device__ __forceinline__ float bf2f(short h){
  union { uint32_t u; float f; } v; v.u = ((uint32_t)(uint16_t)h) << 16;
  return v.f;
}

#define GLOAD16(g, l) __builtin_amdgcn_global_load_lds( \
    (const __attribute__((address_space(1))) void*)(g), \
    (__attribute__((address_space(3))) void*)(l), 16, 0, 0)

// ---------------- gather + residual ----------------
__global__ void gather_kernel(const float* __restrict__ xp, const int* __restrict__ bnd,
                              const float* __restrict__ xr, float* __restrict__ x){
  int t = blockIdx.x, b = blockIdx.y, tid = threadIdx.x;
  int lo = 0, hi = CKB;
  while (lo < hi){ int mid = (lo + hi) >> 1; if (bnd[b*CKB + mid] <= t) lo = mid + 1; else hi = mid; }
  const float4* s  = (const float4*)(xp + ((size_t)b*CKB + lo)*CD);
  const float4* rr = (const float4*)(xr + ((size_t)b*CT + t)*CD);
  float4* dst      = (float4*)(x  + ((size_t)b*CT + t)*CD);
  float4 a = s[tid], c = rr[tid];
  float4 o; o.x = a.x + c.x; o.y = a.y + c.y; o.z = a.z + c.z; o.w = a.w + c.w;
  dst[tid] = o;
}

// ---------------- weight fp32 -> bf16 transpose ----------------
__global__ void wtrans_kernel(const float* __restrict__ W, short* __restrict__ dst,
                              int Kd, int Nd){
  __shared__ __align__(16) float tile[64*65];
  int n0 = blockIdx.x*64, k0 = blockIdx.y*64;
  #pragma unroll
  for (int i = 0; i < 16; ++i){
    int e = threadIdx.x + 256*i; int kl = e >> 6, nl = e & 63;
    tile[kl*65 + nl] = W[(size_t)(k0 + kl)*Nd + n0 + nl];
  }
  __syncthreads();
  #pragma unroll
  for (int i = 0; i < 16; ++i){
    int e = threadIdx.x + 256*i; int nl = e >> 6, kl = e & 63;
    dst[(size_t)(n0 + nl)*Kd + k0 + kl] = f2bf(tile[kl*65 + nl]);
  }
}

// ---------------- RMSNorm ----------------
template<int OUT_BF16>
__global__ void rmsnorm_kernel(const float* __restrict__ x, const float* __restrict__ w,
                               void* __restrict__ outv){
  int row = blockIdx.x, tid = threadIdx.x;
  const float4 xv = ((const float4*)(x + (size_t)row*CD))[tid];
  float ss = xv.x*xv.x + xv.y*xv.y + xv.z*xv.z + xv.w*xv.w;
  #pragma unroll
  for (int m = 1; m < 64; m <<= 1) ss += __shfl_xor(ss, m);
  __shared__ float red[4];
  if ((tid & 63) == 0) red[tid >> 6] = ss;
  __syncthreads();
  float tot = red[0] + red[1] + red[2] + red[3];
  float scale = rsqrtf(tot * (1.0f/1024.0f) + 1e-5f);
  const float4 wv = ((const float4*)w)[tid];
  if (OUT_BF16){
    short4 o;
    o.x = f2bf(xv.x*scale*wv.x); o.y = f2bf(xv.y*scale*wv.y);
    o.z = f2bf(xv.z*scale*wv.z); o.w = f2bf(xv.w*scale*wv.w);
    ((short4*)outv)[(size_t)row*256 + tid] = o;
  } else {
    float4 o;
    o.x = xv.x*scale*wv.x; o.y = xv.y*scale*wv.y;
    o.z = xv.z*scale*wv.z; o.w = xv.w*scale*wv.w;
    ((float4*)outv)[(size_t)row*256 + tid] = o;
  }
}

// ---------------- GEMM: C[M,N] = A[M,K](bf16) * Bt[N,K](bf16)^T ----------------
// 2-phase double-buffered (T3 minimum) + bijective XCD swizzle + grouped-M raster.
// grid is 1-D = NX*NY; NY = M/128, NX = N/128.
template<int EPI>
__global__ __launch_bounds__(256) void gemm_bt(const short* __restrict__ A,
                                               const short* __restrict__ Bt,
                                               void* __restrict__ Cv,
                                               int M, int N, int K,
                                               int NX, int NY){
  __shared__ __align__(16) short sA[2][128*32];
  __shared__ __align__(16) short sB[2][128*32];
  const int tid = threadIdx.x;
  const int lane = tid & 63, wid = tid >> 6;
  const int wm = wid >> 1, wn = wid & 1;
  const int lr = lane & 15, lg = lane >> 4;

  // bijective XCD swizzle (m204) then grouped-M raster (GM=8)
  const int nwg = NX*NY;
  const int orig = blockIdx.x;
  const int qq = nwg >> 3, rr8 = nwg & 7;
  const int xcd = orig & 7, loc = orig >> 3;
  const int wgid = (xcd < rr8 ? xcd*(qq+1) : rr8*(qq+1) + (xcd-rr8)*qq) + loc;
  const int GM = 8;
  const int gsz = GM * NX;
  const int gidg = wgid / gsz;
  const int remg = wgid - gidg*gsz;
  const int bm = gidg*GM + (remg % GM);
  const int bn = remg / GM;
  const int bm0 = bm * 128, bn0 = bn * 128;

  f32x4 acc[4][4];
  #pragma unroll
  for (int i = 0; i < 4; ++i)
    #pragma unroll
    for (int j = 0; j < 4; ++j) acc[i][j] = (f32x4){0.f,0.f,0.f,0.f};

  const short* gA = A  + (size_t)(bm0 + wid*32 + (lane >> 2))*K + (lane & 3)*8;
  const short* gB = Bt + (size_t)(bn0 + wid*32 + (lane >> 2))*K + (lane & 3)*8;

  // prologue: stage K-step 0 into buf 0
  #pragma unroll
  for (int iss = 0; iss < 2; ++iss){
    GLOAD16(gA + (size_t)iss*16*K, &sA[0][wid*1024 + iss*16*32]);
    GLOAD16(gB + (size_t)iss*16*K, &sB[0][wid*1024 + iss*16*32]);
  }
  __syncthreads();   // implicit vmcnt(0) drain

  int cur = 0;
  for (int k0 = 0; k0 < K; k0 += 32){
    // issue next tile's stage first — overlaps with this tile's compute
    if (k0 + 32 < K){
      #pragma unroll
      for (int iss = 0; iss < 2; ++iss){
        GLOAD16(gA + (size_t)iss*16*K + k0 + 32, &sA[cur^1][wid*1024 + iss*16*32]);
        GLOAD16(gB + (size_t)iss*16*K + k0 + 32, &sB[cur^1][wid*1024 + iss*16*32]);
      }
    }
    s16x8 af[4], bq[4];
    #pragma unroll
    for (int i = 0; i < 4; ++i) af[i] = *(const s16x8*)&sA[cur][(wm*64 + i*16 + lr)*32 + lg*8];
    #pragma unroll
    for (int j = 0; j < 4; ++j) bq[j] = *(const s16x8*)&sB[cur][(wn*64 + j*16 + lr)*32 + lg*8];
    #pragma unroll
    for (int i = 0; i < 4; ++i)
      #pragma unroll
      for (int j = 0; j < 4; ++j)
        acc[i][j] = __builtin_amdgcn_mfma_f32_16x16x32_bf16(af[i], bq[j], acc[i][j], 0, 0, 0);
    __syncthreads();   // drains vmcnt(0): next buf ready; all waves done reading cur
    cur ^= 1;
  }

  if (EPI == 0){
    short* C = (short*)Cv;
    #pragma unroll
    for (int i = 0; i < 4; ++i){
      int row0 = bm0 + wm*64 + i*16 + lg*4;
      #pragma unroll
      for (int j = 0; j < 4; ++j){
        int col = bn0 + wn*64 + j*16 + lr;
        #pragma unroll
        for (int r = 0; r < 4; ++r) C[(size_t)(row0 + r)*N + col] = f2bf(acc[i][j][r]);
      }
    }
  } else {
    float* C = (float*)Cv;
    #pragma unroll
    for (int i = 0; i < 4; ++i){
      int row0 = bm0 + wm*64 + i*16 + lg*4;
      #pragma unroll
      for (int j = 0; j < 4; ++j){
        int col = bn0 + wn*64 + j*16 + lr;
        #pragma unroll
        for (int r = 0; r < 4; ++r) C[(size_t)(row0 + r)*N + col] += acc[i][j][r];
      }
    }
  }
}

// ---------------- RoPE ----------------
__global__ void rope_kernel(const short* __restrict__ qkv, const float* __restrict__ cosb,
                            const float* __restrict__ sinb, short* __restrict__ Qo,
                            short* __restrict__ Ko){
  int g = blockIdx.x*256 + threadIdx.x;
  int d = g & 31;
  int h = (g >> 5) & 15;
  int t = (g >> 9) & 2047;
  int b = g >> 20;
  size_t row = (size_t)b*CT + t;
  const short* src = qkv + row*3072 + h*64;
  float q0 = bf2f(src[d]),        q1 = bf2f(src[d+32]);
  float k0 = bf2f(src[1024+d]),   k1 = bf2f(src[1024+d+32]);
  float c0 = cosb[t*64 + d], c1 = cosb[t*64 + d + 32];
  float s0 = sinb[t*64 + d], s1 = sinb[t*64 + d + 32];
  size_t o = row*CD + h*64;
  const float sc = 0.125f;
  Qo[o + d]      = f2bf((q0*c0 - q1*s0)*sc);
  Qo[o + d + 32] = f2bf((q1*c1 + q0*s1)*sc);
  Ko[o + d]      = f2bf(k0*c0 - k1*s0);
  Ko[o + d + 32] = f2bf(k1*c1 + k0*s1);
}

// ---------------- V transpose ----------------
__global__ void vtrans_kernel(const short* __restrict__ qkv, short* __restrict__ Vt){
  __shared__ __align__(16) short tile[64*65];
  int t0 = blockIdx.x*64;
  int h = blockIdx.y & 15, b = blockIdx.y >> 4;
  #pragma unroll
  for (int i = 0; i < 16; ++i){
    int e = threadIdx.x + 256*i; int tl = e >> 6, d = e & 63;
    tile[tl*65 + d] = qkv[(size_t)(b*CT + t0 + tl)*3072 + 2048 + h*64 + d];
  }
  __syncthreads();
  #pragma unroll
  for (int i = 0; i < 16; ++i){
    int e = threadIdx.x + 256*i; int dl = e >> 6, tl = e & 63;
    Vt[((size_t)(b*CNH + h)*CHD + dl)*CT + t0 + tl] = tile[tl*65 + dl];
  }
}

// ---------------- causal flash attention ----------------
__global__ __launch_bounds__(256) void attn_kernel(const short* __restrict__ Q,
                                                   const short* __restrict__ Kb,
                                                   const short* __restrict__ Vt,
                                                   short* __restrict__ O){
  __shared__ __align__(16) short Kl[64*72];
  __shared__ __align__(16) short Vl[64*72];
  __shared__ __align__(16) short Pl[4][32*72];
  const int tid = threadIdx.x, lane = tid & 63, w = tid >> 6;
  const int qblk = gridDim.x - 1 - blockIdx.x;
  const int h = blockIdx.y, b = blockIdx.z;
  const int lr = lane & 15, lg = lane >> 4;
  const int wq0 = qblk*128 + w*32;

  s16x8 qf[2][2];
  #pragma unroll
  for (int qh = 0; qh < 2; ++qh){
    const short* qp = Q + ((size_t)(b*CT + wq0 + qh*16 + lr)*CNH + h)*CHD + lg*8;
    qf[qh][0] = *(const s16x8*)qp;
    qf[qh][1] = *(const s16x8*)(qp + 32);
  }
  f32x4 oacc[2][4];
  #pragma unroll
  for (int qh = 0; qh < 2; ++qh)
    #pragma unroll
    for (int dt = 0; dt < 4; ++dt) oacc[qh][dt] = (f32x4){0.f,0.f,0.f,0.f};
  float m_r[2] = {-1e30f,-1e30f};
  float l_r[2] = {0.f,0.f};

  const int jmax = 2*qblk + 2;
  const short* gK = Kb + (size_t)b*CT*CD + h*CHD;
  const short* gV = Vt + (size_t)(b*CNH + h)*CHD*CT;
  const int srow0 = tid >> 3, scol = (tid & 7)*8;

  {
    #pragma unroll
    for (int p = 0; p < 2; ++p){
      int row = srow0 + p*32;
      s16x8 k0 = *(const s16x8*)(gK + (size_t)row*CD + scol);
      s16x8 v0 = *(const s16x8*)(gV + (size_t)row*CT + scol);
      *(s16x8*)&Kl[row*72 + scol] = k0;
      *(s16x8*)&Vl[row*72 + scol] = v0;
    }
  }
  __syncthreads();

  for (int j = 0; j < jmax; ++j){
    const int kv0 = j*64;
    s16x8 nk[2], nv[2];
    const bool havenext = (j + 1 < jmax);
    if (havenext){
      const int kv1 = kv0 + 64;
      #pragma unroll
      for (int p = 0; p < 2; ++p){
        int row = srow0 + p*32;
        nk[p] = *(const s16x8*)(gK + (size_t)(kv1 + row)*CD + scol);
        nv[p] = *(const s16x8*)(gV + (size_t)row*CT + kv1 + scol);
      }
    }

    if (kv0 < wq0 + 32){
      f32x4 sc[2][4];
      #pragma unroll
      for (int nt = 0; nt < 4; ++nt){
        s16x8 k0 = *(const s16x8*)&Kl[(nt*16 + lr)*72 + lg*8];
        s16x8 k1 = *(const s16x8*)&Kl[(nt*16 + lr)*72 + 32 + lg*8];
        #pragma unroll
        for (int qh = 0; qh < 2; ++qh){
          f32x4 z = (f32x4){0.f,0.f,0.f,0.f};
          z = __builtin_amdgcn_mfma_f32_16x16x32_bf16(k0, qf[qh][0], z, 0, 0, 0);
          z = __builtin_amdgcn_mfma_f32_16x16x32_bf16(k1, qf[qh][1], z, 0, 0, 0);
          sc[qh][nt] = z;
        }
      }
      if (kv0 + 64 > wq0){
        #pragma unroll
        for (int qh = 0; qh < 2; ++qh)
          #pragma unroll
          for (int nt = 0; nt < 4; ++nt)
            #pragma unroll
            for (int r = 0; r < 4; ++r)
              if (kv0 + nt*16 + lg*4 + r > wq0 + qh*16 + lr) sc[qh][nt][r] = -1e30f;
      }
      #pragma unroll
      for (int qh = 0; qh < 2; ++qh){
        float mx = sc[qh][0][0];
        #pragma unroll
        for (int nt = 0; nt < 4; ++nt)
          #pragma unroll
          for (int r = 0; r < 4; ++r) mx = fmaxf(mx, sc[qh][nt][r]);
        mx = fmaxf(mx, __shfl_xor(mx, 16));
        mx = fmaxf(mx, __shfl_xor(mx, 32));
        float mn = fmaxf(m_r[qh], mx);
        float corr = __expf(m_r[qh] - mn);
        m_r[qh] = mn;
        float rs = 0.f;
        #pragma unroll
        for (int nt = 0; nt < 4; ++nt)
          #pragma unroll
          for (int r = 0; r < 4; ++r){
            float pv = __expf(sc[qh][nt][r] - mn);
            rs += pv;
            Pl[w][(qh*16 + lr)*72 + nt*16 + lg*4 + r] = f2bf(pv);
          }
        rs += __shfl_xor(rs, 16);
        rs += __shfl_xor(rs, 32);
        l_r[qh] = l_r[qh]*corr + rs;
        #pragma unroll
        for (int r = 0; r < 4; ++r){
          float c4 = __shfl(corr, lg*4 + r);
          #pragma unroll
          for (int dt = 0; dt < 4; ++dt) oacc[qh][dt][r] *= c4;
        }
      }
      s16x8 pa[2][2];
      #pragma unroll
      for (int qh = 0; qh < 2; ++qh){
        pa[qh][0] = *(const s16x8*)&Pl[w][(qh*16 + lr)*72 + lg*8];
        pa[qh][1] = *(const s16x8*)&Pl[w][(qh*16 + lr)*72 + 32 + lg*8];
      }
      #pragma unroll
      for (int dt = 0; dt < 4; ++dt){
        s16x8 v0 = *(const s16x8*)&Vl[(dt*16 + lr)*72 + lg*8];
        s16x8 v1 = *(const s16x8*)&Vl[(dt*16 + lr)*72 + 32 + lg*8];
        #pragma unroll
        for (int qh = 0; qh < 2; ++qh){
          oacc[qh][dt] = __builtin_amdgcn_mfma_f32_16x16x32_bf16(pa[qh][0], v0, oacc[qh][dt], 0, 0, 0);
          oacc[qh][dt] = __builtin_amdgcn_mfma_f32_16x16x32_bf16(pa[qh][1], v1, oacc[qh][dt], 0, 0, 0);
        }
      }
    }
    __syncthreads();
    if (havenext){
      #pragma unroll
      for (int p = 0; p < 2; ++p){
        int row = srow0 + p*32;
        *(s16x8*)&Kl[row*72 + scol] = nk[p];
        *(s16x8*)&Vl[row*72 + scol] = nv[p];
      }
    }
    __syncthreads();
  }

  #pragma unroll
  for (int qh = 0; qh < 2; ++qh)
    #pragma unroll
    for (int r = 0; r < 4; ++r){
      float lf = __shfl(l_r[qh], lg*4 + r);
      float inv = 1.f / lf;
      int qrow = wq0 + qh*16 + lg*4 + r;
      #pragma unroll
      for (int dt = 0; dt < 4; ++dt)
        O[((size_t)(b*CT + qrow)*CNH + h)*CHD + dt*16 + lr] = f2bf(oacc[qh][dt][r] * inv);
    }
}

// ---------------- SiLU(u) * g ----------------
__global__ void silu_kernel(const short* __restrict__ ug, short* __restrict__ m){
  int g = blockIdx.x*256 + threadIdx.x;
  int col4 = g & 1023; int row = g >> 10;
  short4 u  = *(const short4*)&ug[(size_t)row*8192 + col4*4];
  short4 gg = *(const short4*)&ug[(size_t)row*8192 + 4096 + col4*4];
  short4 o;
  {
    float a = bf2f(u.x), bb = bf2f(gg.x); o.x = f2bf(a / (1.f + __expf(-a)) * bb);
    a = bf2f(u.y); bb = bf2f(gg.y); o.y = f2bf(a / (1.f + __expf(-a)) * bb);
    a = bf2f(u.z); bb = bf2f(gg.z); o.z = f2bf(a / (1.f + __expf(-a)) * bb);
    a = bf2f(u.w); bb = bf2f(gg.w); o.w = f2bf(a / (1.f + __expf(-a)) * bb);
  }
  *(short4*)&m[(size_t)row*4096 + col4*4] = o;
}

// ---------------- launch ----------------
extern "C" void kernel_launch(void* const* d_in, const int* in_sizes, int n_in,
                              void* d_out, int out_size, void* d_ws, size_t ws_size,
                              hipStream_t stream){
  (void)in_sizes; (void)n_in; (void)out_size; (void)ws_size;
  const float* x_processed = (const float*)d_in[0];
  const int*   boundaries  = (const int*)d_in[1];
  const float* x_residual  = (const float*)d_in[3];
  const float* cosb        = (const float*)d_in[4];
  const float* sinb        = (const float*)d_in[5];
  const float* wq          = (const float*)d_in[7];
  const float* wk          = (const float*)d_in[8];
  const float* wv          = (const float*)d_in[9];
  const float* wo          = (const float*)d_in[10];
  const float* attn_nw     = (const float*)d_in[11];
  const float* mlp_nw      = (const float*)d_in[12];
  const float* w1          = (const float*)d_in[13];
  const float* w3          = (const float*)d_in[14];
  const float* w2          = (const float*)d_in[15];
  const float* final_nw    = (const float*)d_in[16];

  char* p = (char*)d_ws;
  auto alloc = [&](size_t bytes)->char*{
    char* r = p; p += (bytes + 255) & ~(size_t)255; return r;
  };
  short* wqkvT = (short*)alloc((size_t)2*3072*1024*2);
  short* woT   = (short*)alloc((size_t)2*1024*1024*2);
  short* w13T  = (short*)alloc((size_t)2*8192*1024*2);
  short* w2T   = (short*)alloc((size_t)2*1024*4096*2);
  float* x     = (float*)alloc((size_t)4096*1024*4);
  short* hbuf  = (short*)alloc((size_t)4096*1024*2);
  short* qkv   = (short*)alloc((size_t)4096*3072*2);
  short* qr    = (short*)alloc((size_t)4096*1024*2);
  short* kr    = (short*)alloc((size_t)4096*1024*2);
  short* vt    = (short*)alloc((size_t)4096*1024*2);
  short* obuf  = (short*)alloc((size_t)4096*1024*2);
  short* ug    = (short*)alloc((size_t)4096*8192*2);
  short* mbuf  = (short*)alloc((size_t)4096*4096*2);

  for (int l = 0; l < 2; ++l){
    size_t wOff = (size_t)l*1024*1024;
    wtrans_kernel<<<dim3(16,16),256,0,stream>>>(wq + wOff, wqkvT + (size_t)l*3072*1024,                     1024, 1024);
    wtrans_kernel<<<dim3(16,16),256,0,stream>>>(wk + wOff, wqkvT + (size_t)l*3072*1024 + (size_t)1024*1024, 1024, 1024);
    wtrans_kernel<<<dim3(16,16),256,0,stream>>>(wv + wOff, wqkvT + (size_t)l*3072*1024 + (size_t)2048*1024, 1024, 1024);
    wtrans_kernel<<<dim3(16,16),256,0,stream>>>(wo + wOff, woT + (size_t)l*1024*1024,                       1024, 1024);
    wtrans_kernel<<<dim3(64,16),256,0,stream>>>(w1 + (size_t)l*1024*4096, w13T + (size_t)l*8192*1024,                     1024, 4096);
    wtrans_kernel<<<dim3(64,16),256,0,stream>>>(w3 + (size_t)l*1024*4096, w13T + (size_t)l*8192*1024 + (size_t)4096*1024, 1024, 4096);
    wtrans_kernel<<<dim3(16,64),256,0,stream>>>(w2 + (size_t)l*4096*1024, w2T + (size_t)l*1024*4096,                      4096, 1024);
  }
  gather_kernel<<<dim3(2048,2),256,0,stream>>>(x_processed, boundaries, x_residual, x);
  for (int l = 0; l < 2; ++l){
    rmsnorm_kernel<1><<<4096,256,0,stream>>>(x, attn_nw + l*1024, hbuf);
    gemm_bt<0><<<24*32,256,0,stream>>>(hbuf, wqkvT + (size_t)l*3072*1024, qkv, 4096, 3072, 1024, 24, 32);
    rope_kernel<<<8192,256,0,stream>>>(qkv, cosb, sinb, qr, kr);
    vtrans_kernel<<<dim3(32,32),256,0,stream>>>(qkv, vt);
    attn_kernel<<<dim3(16,16,2),256,0,stream>>>(qr, kr, vt, obuf);
    gemm_bt<1><<<8*32,256,0,stream>>>(obuf, woT + (size_t)l*1024*1024, x, 4096, 1024, 1024, 8, 32);
    rmsnorm_kernel<1><<<4096,256,0,stream>>>(x, mlp_nw + l*1024, hbuf);
    gemm_bt<0><<<64*32,256,0,stream>>>(hbuf, w13T + (size_t)l*8192*1024, ug, 4096, 8192, 1024, 64, 32);
    silu_kernel<<<16384,256,0,stream>>>(ug, mbuf);
    gemm_bt<1><<<8*32,256,0,stream>>>(mbuf, w2T + (size_t)l*1024*4096, x, 4096, 1024, 4096, 8, 32);
  }
  rmsnorm_kernel<0><<<4096,256,0,stream>>>(x, final_nw, d_out);
}

// Round 4
// 796.162 us; speedup vs baseline: 1.3792x; 1.0190x over previous
//
#include <hip/hip_runtime.h>
#include <stdint.h>

typedef __attribute__((ext_vector_type(8))) short s16x8;
typedef __attribute__((ext_vector_type(4))) float f32x4;

#define CB 2
#define CT 2048
#define CD 1024
#define CNH 16
#define CHD 64
#define CDFF 4096
#define CKB 512

__device__ __forceinline__ short f2bf(float f){
  union { float f; uint32_t u; } v; v.f = f;
  uint32_t r = v.u + 0x7FFFu + ((v.u >> 16) & 1u);
  return (short)(r >> 16);
}
__device__ __forceinline__ float bf2f(short h){
  union { uint32_t u; float f; } v; v.u = ((uint32_t)(uint16_t)h) << 16;
  return v.f;
}

#define GLOAD16(g, l) __builtin_amdgcn_global_load_lds( \
    (const __attribute__((address_space(1))) void*)(g), \
    (__attribute__((address_space(3))) void*)(l), 16, 0, 0)

// ---------------- gather + residual ----------------
__global__ void gather_kernel(const float* __restrict__ xp, const int* __restrict__ bnd,
                              const float* __restrict__ xr, float* __restrict__ x){
  int t = blockIdx.x, b = blockIdx.y, tid = threadIdx.x;
  int lo = 0, hi = CKB;
  while (lo < hi){ int mid = (lo + hi) >> 1; if (bnd[b*CKB + mid] <= t) lo = mid + 1; else hi = mid; }
  const float4* s  = (const float4*)(xp + ((size_t)b*CKB + lo)*CD);
  const float4* rr = (const float4*)(xr + ((size_t)b*CT + t)*CD);
  float4* dst      = (float4*)(x  + ((size_t)b*CT + t)*CD);
  float4 a = s[tid], c = rr[tid];
  float4 o; o.x = a.x + c.x; o.y = a.y + c.y; o.z = a.z + c.z; o.w = a.w + c.w;
  dst[tid] = o;
}

// ---------------- weight fp32 -> bf16 transpose ----------------
__global__ void wtrans_kernel(const float* __restrict__ W, short* __restrict__ dst,
                              int Kd, int Nd){
  __shared__ __align__(16) float tile[64*65];
  int n0 = blockIdx.x*64, k0 = blockIdx.y*64;
  #pragma unroll
  for (int i = 0; i < 16; ++i){
    int e = threadIdx.x + 256*i; int kl = e >> 6, nl = e & 63;
    tile[kl*65 + nl] = W[(size_t)(k0 + kl)*Nd + n0 + nl];
  }
  __syncthreads();
  #pragma unroll
  for (int i = 0; i < 16; ++i){
    int e = threadIdx.x + 256*i; int nl = e >> 6, kl = e & 63;
    dst[(size_t)(n0 + nl)*Kd + k0 + kl] = f2bf(tile[kl*65 + nl]);
  }
}

// ---------------- RMSNorm ----------------
template<int OUT_BF16>
__global__ void rmsnorm_kernel(const float* __restrict__ x, const float* __restrict__ w,
                               void* __restrict__ outv){
  int row = blockIdx.x, tid = threadIdx.x;
  const float4 xv = ((const float4*)(x + (size_t)row*CD))[tid];
  float ss = xv.x*xv.x + xv.y*xv.y + xv.z*xv.z + xv.w*xv.w;
  #pragma unroll
  for (int m = 1; m < 64; m <<= 1) ss += __shfl_xor(ss, m);
  __shared__ float red[4];
  if ((tid & 63) == 0) red[tid >> 6] = ss;
  __syncthreads();
  float tot = red[0] + red[1] + red[2] + red[3];
  float scale = rsqrtf(tot * (1.0f/1024.0f) + 1e-5f);
  const float4 wv = ((const float4*)w)[tid];
  if (OUT_BF16){
    short4 o;
    o.x = f2bf(xv.x*scale*wv.x); o.y = f2bf(xv.y*scale*wv.y);
    o.z = f2bf(xv.z*scale*wv.z); o.w = f2bf(xv.w*scale*wv.w);
    ((short4*)outv)[(size_t)row*256 + tid] = o;
  } else {
    float4 o;
    o.x = xv.x*scale*wv.x; o.y = xv.y*scale*wv.y;
    o.z = xv.z*scale*wv.z; o.w = xv.w*scale*wv.w;
    ((float4*)outv)[(size_t)row*256 + tid] = o;
  }
}

// ---------------- block-index swizzle helper (m204 bijective XCD + GM raster) ---
__device__ __forceinline__ void swz_block(int NX, int NY, int& bm, int& bn){
  const int nwg = NX*NY;
  const int orig = blockIdx.x;
  const int qq = nwg >> 3, rr8 = nwg & 7;
  const int xcd = orig & 7, loc = orig >> 3;
  const int wgid = (xcd < rr8 ? xcd*(qq+1) : rr8*(qq+1) + (xcd-rr8)*qq) + loc;
  const int GM = 8;
  const int gsz = GM * NX;
  const int gidg = wgid / gsz;
  const int remg = wgid - gidg*gsz;
  bm = gidg*GM + (remg % GM);
  bn = remg / GM;
}

// ---------------- GEMM 2-phase 128x128 (kept for small-N GEMMs) ----------------
template<int EPI>
__global__ __launch_bounds__(256) void gemm_bt(const short* __restrict__ A,
                                               const short* __restrict__ Bt,
                                               void* __restrict__ Cv,
                                               int M, int N, int K,
                                               int NX, int NY){
  __shared__ __align__(16) short sA[2][128*32];
  __shared__ __align__(16) short sB[2][128*32];
  const int tid = threadIdx.x;
  const int lane = tid & 63, wid = tid >> 6;
  const int wm = wid >> 1, wn = wid & 1;
  const int lr = lane & 15, lg = lane >> 4;
  int bm, bn; swz_block(NX, NY, bm, bn);
  const int bm0 = bm * 128, bn0 = bn * 128;

  f32x4 acc[4][4];
  #pragma unroll
  for (int i = 0; i < 4; ++i)
    #pragma unroll
    for (int j = 0; j < 4; ++j) acc[i][j] = (f32x4){0.f,0.f,0.f,0.f};

  const short* gA = A  + (size_t)(bm0 + wid*32 + (lane >> 2))*K + (lane & 3)*8;
  const short* gB = Bt + (size_t)(bn0 + wid*32 + (lane >> 2))*K + (lane & 3)*8;

  #pragma unroll
  for (int iss = 0; iss < 2; ++iss){
    GLOAD16(gA + (size_t)iss*16*K, &sA[0][wid*1024 + iss*16*32]);
    GLOAD16(gB + (size_t)iss*16*K, &sB[0][wid*1024 + iss*16*32]);
  }
  __syncthreads();

  int cur = 0;
  for (int k0 = 0; k0 < K; k0 += 32){
    if (k0 + 32 < K){
      #pragma unroll
      for (int iss = 0; iss < 2; ++iss){
        GLOAD16(gA + (size_t)iss*16*K + k0 + 32, &sA[cur^1][wid*1024 + iss*16*32]);
        GLOAD16(gB + (size_t)iss*16*K + k0 + 32, &sB[cur^1][wid*1024 + iss*16*32]);
      }
    }
    s16x8 af[4], bq[4];
    #pragma unroll
    for (int i = 0; i < 4; ++i) af[i] = *(const s16x8*)&sA[cur][(wm*64 + i*16 + lr)*32 + lg*8];
    #pragma unroll
    for (int j = 0; j < 4; ++j) bq[j] = *(const s16x8*)&sB[cur][(wn*64 + j*16 + lr)*32 + lg*8];
    #pragma unroll
    for (int i = 0; i < 4; ++i)
      #pragma unroll
      for (int j = 0; j < 4; ++j)
        acc[i][j] = __builtin_amdgcn_mfma_f32_16x16x32_bf16(af[i], bq[j], acc[i][j], 0, 0, 0);
    __syncthreads();
    cur ^= 1;
  }

  if (EPI == 0){
    short* C = (short*)Cv;
    #pragma unroll
    for (int i = 0; i < 4; ++i){
      int row0 = bm0 + wm*64 + i*16 + lg*4;
      #pragma unroll
      for (int j = 0; j < 4; ++j){
        int col = bn0 + wn*64 + j*16 + lr;
        #pragma unroll
        for (int r = 0; r < 4; ++r) C[(size_t)(row0 + r)*N + col] = f2bf(acc[i][j][r]);
      }
    }
  } else {
    float* C = (float*)Cv;
    #pragma unroll
    for (int i = 0; i < 4; ++i){
      int row0 = bm0 + wm*64 + i*16 + lg*4;
      #pragma unroll
      for (int j = 0; j < 4; ++j){
        int col = bn0 + wn*64 + j*16 + lr;
        #pragma unroll
        for (int r = 0; r < 4; ++r) C[(size_t)(row0 + r)*N + col] += acc[i][j][r];
      }
    }
  }
}

// ---------------- GEMM 8-phase 256x256, BK=64, 8 waves, counted vmcnt ----------
// LDS: 2 buffers x 4 units (A-kh0, B-kh0, A-kh1, B-kh1) x [256 rows][32 cols] bf16
// = 128 KiB. XOR swizzle: 16B-slot ^= (row>>1)&3 (pre-swizzled global source +
// swizzled ds_read; global_load_lds dest stays linear).
// Phases per K-tile: p0=(Chalf0,k0) p1=(Chalf1,k0) p2=(Chalf0,k1) p3=(Chalf1,k1).
// Prefetch 1 half-tile per phase (2 gloads); vmcnt(4) after MFMA of p1 and p3.
#define STAGE8(u, kt, bufx) do { \
  const short* Gp_ = ((u)&1) ? Bt : A; \
  const int rb_ = ((u)&1) ? bn0 : bm0; \
  const int kh_ = (u)>>1; \
  _Pragma("unroll") \
  for (int L_ = 0; L_ < 2; ++L_){ \
    int rowS_ = L_*128 + wid*16 + (lane>>2); \
    int sp_ = (lane&3) ^ ((rowS_>>1)&3); \
    GLOAD16(Gp_ + (size_t)(rb_ + rowS_)*K + (size_t)(kt)*64 + kh_*32 + sp_*8, \
            &sAB[bufx][u][(L_*512 + wid*64)*8]); \
  } \
} while(0)

#define PHASE8(p, ch, kk) do { \
  if (pf) STAGE8(p, kt+1, nbuf); \
  s16x8 af_[4], bq_[4]; \
  _Pragma("unroll") \
  for (int ii_ = 0; ii_ < 4; ++ii_){ \
    int rowA_ = wm*128 + ((ch)*4 + ii_)*16 + lr; \
    af_[ii_] = *(const s16x8*)&sAB[buf][(kk)*2][rowA_*32 + ((lg ^ ((rowA_>>1)&3))<<3)]; \
  } \
  _Pragma("unroll") \
  for (int j_ = 0; j_ < 4; ++j_){ \
    int rowB_ = wn*64 + j_*16 + lr; \
    bq_[j_] = *(const s16x8*)&sAB[buf][(kk)*2+1][rowB_*32 + ((lg ^ ((rowB_>>1)&3))<<3)]; \
  } \
  __builtin_amdgcn_s_barrier(); \
  asm volatile("s_waitcnt lgkmcnt(0)" ::: "memory"); \
  __builtin_amdgcn_s_setprio(1); \
  _Pragma("unroll") \
  for (int ii_ = 0; ii_ < 4; ++ii_) \
    _Pragma("unroll") \
    for (int j_ = 0; j_ < 4; ++j_) \
      acc[(ch)*4 + ii_][j_] = __builtin_amdgcn_mfma_f32_16x16x32_bf16(af_[ii_], bq_[j_], acc[(ch)*4 + ii_][j_], 0, 0, 0); \
  __builtin_amdgcn_s_setprio(0); \
  if ((p) == 1){ \
    if (pf) asm volatile("s_waitcnt vmcnt(4)" ::: "memory"); \
    else    asm volatile("s_waitcnt vmcnt(0)" ::: "memory"); \
  } \
  if ((p) == 3 && pf) asm volatile("s_waitcnt vmcnt(4)" ::: "memory"); \
  __builtin_amdgcn_s_barrier(); \
} while(0)

__global__ __launch_bounds__(512, 2) void gemm8p(const short* __restrict__ A,
                                                 const short* __restrict__ Bt,
                                                 short* __restrict__ C,
                                                 int M, int N, int K,
                                                 int NX, int NY){
  __shared__ __align__(16) short sAB[2][4][256*32];
  const int tid = threadIdx.x;
  const int lane = tid & 63, wid = tid >> 6;        // 8 waves
  const int wm = wid >> 2, wn = wid & 3;            // 2M x 4N
  const int lr = lane & 15, lg = lane >> 4;
  int bm, bn; swz_block(NX, NY, bm, bn);
  const int bm0 = bm * 256, bn0 = bn * 256;

  f32x4 acc[8][4];
  #pragma unroll
  for (int i = 0; i < 8; ++i)
    #pragma unroll
    for (int j = 0; j < 4; ++j) acc[i][j] = (f32x4){0.f,0.f,0.f,0.f};

  const int NK = K >> 6;
  // prologue: stage K-tile 0 (4 half-tiles, 8 loads); wait for first two units
  STAGE8(0, 0, 0);
  STAGE8(1, 0, 0);
  STAGE8(2, 0, 0);
  STAGE8(3, 0, 0);
  asm volatile("s_waitcnt vmcnt(4)" ::: "memory");
  __builtin_amdgcn_s_barrier();

  #pragma unroll 1
  for (int kt = 0; kt < NK; ++kt){
    const bool pf = (kt + 1 < NK);
    const int buf = kt & 1, nbuf = buf ^ 1;
    PHASE8(0, 0, 0);
    PHASE8(1, 1, 0);
    PHASE8(2, 0, 1);
    PHASE8(3, 1, 1);
  }

  #pragma unroll
  for (int i = 0; i < 8; ++i){
    int row0 = bm0 + wm*128 + i*16 + lg*4;
    #pragma unroll
    for (int j = 0; j < 4; ++j){
      int col = bn0 + wn*64 + j*16 + lr;
      #pragma unroll
      for (int r = 0; r < 4; ++r) C[(size_t)(row0 + r)*N + col] = f2bf(acc[i][j][r]);
    }
  }
}

// ---------------- RoPE ----------------
__global__ void rope_kernel(const short* __restrict__ qkv, const float* __restrict__ cosb,
                            const float* __restrict__ sinb, short* __restrict__ Qo,
                            short* __restrict__ Ko){
  int g = blockIdx.x*256 + threadIdx.x;
  int d = g & 31;
  int h = (g >> 5) & 15;
  int t = (g >> 9) & 2047;
  int b = g >> 20;
  size_t row = (size_t)b*CT + t;
  const short* src = qkv + row*3072 + h*64;
  float q0 = bf2f(src[d]),        q1 = bf2f(src[d+32]);
  float k0 = bf2f(src[1024+d]),   k1 = bf2f(src[1024+d+32]);
  float c0 = cosb[t*64 + d], c1 = cosb[t*64 + d + 32];
  float s0 = sinb[t*64 + d], s1 = sinb[t*64 + d + 32];
  size_t o = row*CD + h*64;
  const float sc = 0.125f;
  Qo[o + d]      = f2bf((q0*c0 - q1*s0)*sc);
  Qo[o + d + 32] = f2bf((q1*c1 + q0*s1)*sc);
  Ko[o + d]      = f2bf(k0*c0 - k1*s0);
  Ko[o + d + 32] = f2bf(k1*c1 + k0*s1);
}

// ---------------- V transpose ----------------
__global__ void vtrans_kernel(const short* __restrict__ qkv, short* __restrict__ Vt){
  __shared__ __align__(16) short tile[64*65];
  int t0 = blockIdx.x*64;
  int h = blockIdx.y & 15, b = blockIdx.y >> 4;
  #pragma unroll
  for (int i = 0; i < 16; ++i){
    int e = threadIdx.x + 256*i; int tl = e >> 6, d = e & 63;
    tile[tl*65 + d] = qkv[(size_t)(b*CT + t0 + tl)*3072 + 2048 + h*64 + d];
  }
  __syncthreads();
  #pragma unroll
  for (int i = 0; i < 16; ++i){
    int e = threadIdx.x + 256*i; int dl = e >> 6, tl = e & 63;
    Vt[((size_t)(b*CNH + h)*CHD + dl)*CT + t0 + tl] = tile[tl*65 + dl];
  }
}

// ---------------- causal flash attention ----------------
__global__ __launch_bounds__(256) void attn_kernel(const short* __restrict__ Q,
                                                   const short* __restrict__ Kb,
                                                   const short* __restrict__ Vt,
                                                   short* __restrict__ O){
  __shared__ __align__(16) short Kl[64*72];
  __shared__ __align__(16) short Vl[64*72];
  __shared__ __align__(16) short Pl[4][32*72];
  const int tid = threadIdx.x, lane = tid & 63, w = tid >> 6;
  const int qblk = gridDim.x - 1 - blockIdx.x;
  const int h = blockIdx.y, b = blockIdx.z;
  const int lr = lane & 15, lg = lane >> 4;
  const int wq0 = qblk*128 + w*32;

  s16x8 qf[2][2];
  #pragma unroll
  for (int qh = 0; qh < 2; ++qh){
    const short* qp = Q + ((size_t)(b*CT + wq0 + qh*16 + lr)*CNH + h)*CHD + lg*8;
    qf[qh][0] = *(const s16x8*)qp;
    qf[qh][1] = *(const s16x8*)(qp + 32);
  }
  f32x4 oacc[2][4];
  #pragma unroll
  for (int qh = 0; qh < 2; ++qh)
    #pragma unroll
    for (int dt = 0; dt < 4; ++dt) oacc[qh][dt] = (f32x4){0.f,0.f,0.f,0.f};
  float m_r[2] = {-1e30f,-1e30f};
  float l_r[2] = {0.f,0.f};

  const int jmax = 2*qblk + 2;
  const short* gK = Kb + (size_t)b*CT*CD + h*CHD;
  const short* gV = Vt + (size_t)(b*CNH + h)*CHD*CT;
  const int srow0 = tid >> 3, scol = (tid & 7)*8;

  {
    #pragma unroll
    for (int p = 0; p < 2; ++p){
      int row = srow0 + p*32;
      s16x8 k0 = *(const s16x8*)(gK + (size_t)row*CD + scol);
      s16x8 v0 = *(const s16x8*)(gV + (size_t)row*CT + scol);
      *(s16x8*)&Kl[row*72 + scol] = k0;
      *(s16x8*)&Vl[row*72 + scol] = v0;
    }
  }
  __syncthreads();

  for (int j = 0; j < jmax; ++j){
    const int kv0 = j*64;
    s16x8 nk[2], nv[2];
    const bool havenext = (j + 1 < jmax);
    if (havenext){
      const int kv1 = kv0 + 64;
      #pragma unroll
      for (int p = 0; p < 2; ++p){
        int row = srow0 + p*32;
        nk[p] = *(const s16x8*)(gK + (size_t)(kv1 + row)*CD + scol);
        nv[p] = *(const s16x8*)(gV + (size_t)row*CT + kv1 + scol);
      }
    }

    if (kv0 < wq0 + 32){
      f32x4 sc[2][4];
      #pragma unroll
      for (int nt = 0; nt < 4; ++nt){
        s16x8 k0 = *(const s16x8*)&Kl[(nt*16 + lr)*72 + lg*8];
        s16x8 k1 = *(const s16x8*)&Kl[(nt*16 + lr)*72 + 32 + lg*8];
        #pragma unroll
        for (int qh = 0; qh < 2; ++qh){
          f32x4 z = (f32x4){0.f,0.f,0.f,0.f};
          z = __builtin_amdgcn_mfma_f32_16x16x32_bf16(k0, qf[qh][0], z, 0, 0, 0);
          z = __builtin_amdgcn_mfma_f32_16x16x32_bf16(k1, qf[qh][1], z, 0, 0, 0);
          sc[qh][nt] = z;
        }
      }
      if (kv0 + 64 > wq0){
        #pragma unroll
        for (int qh = 0; qh < 2; ++qh)
          #pragma unroll
          for (int nt = 0; nt < 4; ++nt)
            #pragma unroll
            for (int r = 0; r < 4; ++r)
              if (kv0 + nt*16 + lg*4 + r > wq0 + qh*16 + lr) sc[qh][nt][r] = -1e30f;
      }
      #pragma unroll
      for (int qh = 0; qh < 2; ++qh){
        float mx = sc[qh][0][0];
        #pragma unroll
        for (int nt = 0; nt < 4; ++nt)
          #pragma unroll
          for (int r = 0; r < 4; ++r) mx = fmaxf(mx, sc[qh][nt][r]);
        mx = fmaxf(mx, __shfl_xor(mx, 16));
        mx = fmaxf(mx, __shfl_xor(mx, 32));
        float mn = fmaxf(m_r[qh], mx);
        float corr = __expf(m_r[qh] - mn);
        m_r[qh] = mn;
        float rs = 0.f;
        #pragma unroll
        for (int nt = 0; nt < 4; ++nt)
          #pragma unroll
          for (int r = 0; r < 4; ++r){
            float pv = __expf(sc[qh][nt][r] - mn);
            rs += pv;
            Pl[w][(qh*16 + lr)*72 + nt*16 + lg*4 + r] = f2bf(pv);
          }
        rs += __shfl_xor(rs, 16);
        rs += __shfl_xor(rs, 32);
        l_r[qh] = l_r[qh]*corr + rs;
        #pragma unroll
        for (int r = 0; r < 4; ++r){
          float c4 = __shfl(corr, lg*4 + r);
          #pragma unroll
          for (int dt = 0; dt < 4; ++dt) oacc[qh][dt][r] *= c4;
        }
      }
      s16x8 pa[2][2];
      #pragma unroll
      for (int qh = 0; qh < 2; ++qh){
        pa[qh][0] = *(const s16x8*)&Pl[w][(qh*16 + lr)*72 + lg*8];
        pa[qh][1] = *(const s16x8*)&Pl[w][(qh*16 + lr)*72 + 32 + lg*8];
      }
      #pragma unroll
      for (int dt = 0; dt < 4; ++dt){
        s16x8 v0 = *(const s16x8*)&Vl[(dt*16 + lr)*72 + lg*8];
        s16x8 v1 = *(const s16x8*)&Vl[(dt*16 + lr)*72 + 32 + lg*8];
        #pragma unroll
        for (int qh = 0; qh < 2; ++qh){
          oacc[qh][dt] = __builtin_amdgcn_mfma_f32_16x16x32_bf16(pa[qh][0], v0, oacc[qh][dt], 0, 0, 0);
          oacc[qh][dt] = __builtin_amdgcn_mfma_f32_16x16x32_bf16(pa[qh][1], v1, oacc[qh][dt], 0, 0, 0);
        }
      }
    }
    __syncthreads();
    if (havenext){
      #pragma unroll
      for (int p = 0; p < 2; ++p){
        int row = srow0 + p*32;
        *(s16x8*)&Kl[row*72 + scol] = nk[p];
        *(s16x8*)&Vl[row*72 + scol] = nv[p];
      }
    }
    __syncthreads();
  }

  #pragma unroll
  for (int qh = 0; qh < 2; ++qh)
    #pragma unroll
    for (int r = 0; r < 4; ++r){
      float lf = __shfl(l_r[qh], lg*4 + r);
      float inv = 1.f / lf;
      int qrow = wq0 + qh*16 + lg*4 + r;
      #pragma unroll
      for (int dt = 0; dt < 4; ++dt)
        O[((size_t)(b*CT + qrow)*CNH + h)*CHD + dt*16 + lr] = f2bf(oacc[qh][dt][r] * inv);
    }
}

// ---------------- SiLU(u) * g ----------------
__global__ void silu_kernel(const short* __restrict__ ug, short* __restrict__ m){
  int g = blockIdx.x*256 + threadIdx.x;
  int col4 = g & 1023; int row = g >> 10;
  short4 u  = *(const short4*)&ug[(size_t)row*8192 + col4*4];
  short4 gg = *(const short4*)&ug[(size_t)row*8192 + 4096 + col4*4];
  short4 o;
  {
    float a = bf2f(u.x), bb = bf2f(gg.x); o.x = f2bf(a / (1.f + __expf(-a)) * bb);
    a = bf2f(u.y); bb = bf2f(gg.y); o.y = f2bf(a / (1.f + __expf(-a)) * bb);
    a = bf2f(u.z); bb = bf2f(gg.z); o.z = f2bf(a / (1.f + __expf(-a)) * bb);
    a = bf2f(u.w); bb = bf2f(gg.w); o.w = f2bf(a / (1.f + __expf(-a)) * bb);
  }
  *(short4*)&m[(size_t)row*4096 + col4*4] = o;
}

// ---------------- launch ----------------
extern "C" void kernel_launch(void* const* d_in, const int* in_sizes, int n_in,
                              void* d_out, int out_size, void* d_ws, size_t ws_size,
                              hipStream_t stream){
  (void)in_sizes; (void)n_in; (void)out_size; (void)ws_size;
  const float* x_processed = (const float*)d_in[0];
  const int*   boundaries  = (const int*)d_in[1];
  const float* x_residual  = (const float*)d_in[3];
  const float* cosb        = (const float*)d_in[4];
  const float* sinb        = (const float*)d_in[5];
  const float* wq          = (const float*)d_in[7];
  const float* wk          = (const float*)d_in[8];
  const float* wv          = (const float*)d_in[9];
  const float* wo          = (const float*)d_in[10];
  const float* attn_nw     = (const float*)d_in[11];
  const float* mlp_nw      = (const float*)d_in[12];
  const float* w1          = (const float*)d_in[13];
  const float* w3          = (const float*)d_in[14];
  const float* w2          = (const float*)d_in[15];
  const float* final_nw    = (const float*)d_in[16];

  char* p = (char*)d_ws;
  auto alloc = [&](size_t bytes)->char*{
    char* r = p; p += (bytes + 255) & ~(size_t)255; return r;
  };
  short* wqkvT = (short*)alloc((size_t)2*3072*1024*2);
  short* woT   = (short*)alloc((size_t)2*1024*1024*2);
  short* w13T  = (short*)alloc((size_t)2*8192*1024*2);
  short* w2T   = (short*)alloc((size_t)2*1024*4096*2);
  float* x     = (float*)alloc((size_t)4096*1024*4);
  short* hbuf  = (short*)alloc((size_t)4096*1024*2);
  short* qkv   = (short*)alloc((size_t)4096*3072*2);
  short* qr    = (short*)alloc((size_t)4096*1024*2);
  short* kr    = (short*)alloc((size_t)4096*1024*2);
  short* vt    = (short*)alloc((size_t)4096*1024*2);
  short* obuf  = (short*)alloc((size_t)4096*1024*2);
  short* ug    = (short*)alloc((size_t)4096*8192*2);
  short* mbuf  = (short*)alloc((size_t)4096*4096*2);

  for (int l = 0; l < 2; ++l){
    size_t wOff = (size_t)l*1024*1024;
    wtrans_kernel<<<dim3(16,16),256,0,stream>>>(wq + wOff, wqkvT + (size_t)l*3072*1024,                     1024, 1024);
    wtrans_kernel<<<dim3(16,16),256,0,stream>>>(wk + wOff, wqkvT + (size_t)l*3072*1024 + (size_t)1024*1024, 1024, 1024);
    wtrans_kernel<<<dim3(16,16),256,0,stream>>>(wv + wOff, wqkvT + (size_t)l*3072*1024 + (size_t)2048*1024, 1024, 1024);
    wtrans_kernel<<<dim3(16,16),256,0,stream>>>(wo + wOff, woT + (size_t)l*1024*1024,                       1024, 1024);
    wtrans_kernel<<<dim3(64,16),256,0,stream>>>(w1 + (size_t)l*1024*4096, w13T + (size_t)l*8192*1024,                     1024, 4096);
    wtrans_kernel<<<dim3(64,16),256,0,stream>>>(w3 + (size_t)l*1024*4096, w13T + (size_t)l*8192*1024 + (size_t)4096*1024, 1024, 4096);
    wtrans_kernel<<<dim3(16,64),256,0,stream>>>(w2 + (size_t)l*4096*1024, w2T + (size_t)l*1024*4096,                      4096, 1024);
  }
  gather_kernel<<<dim3(2048,2),256,0,stream>>>(x_processed, boundaries, x_residual, x);
  for (int l = 0; l < 2; ++l){
    rmsnorm_kernel<1><<<4096,256,0,stream>>>(x, attn_nw + l*1024, hbuf);
    gemm8p<<<12*16,512,0,stream>>>(hbuf, wqkvT + (size_t)l*3072*1024, qkv, 4096, 3072, 1024, 12, 16);
    rope_kernel<<<8192,256,0,stream>>>(qkv, cosb, sinb, qr, kr);
    vtrans_kernel<<<dim3(32,32),256,0,stream>>>(qkv, vt);
    attn_kernel<<<dim3(16,16,2),256,0,stream>>>(qr, kr, vt, obuf);
    gemm_bt<1><<<8*32,256,0,stream>>>(obuf, woT + (size_t)l*1024*1024, x, 4096, 1024, 1024, 8, 32);
    rmsnorm_kernel<1><<<4096,256,0,stream>>>(x, mlp_nw + l*1024, hbuf);
    gemm8p<<<32*16,512,0,stream>>>(hbuf, w13T + (size_t)l*8192*1024, ug, 4096, 8192, 1024, 32, 16);
    silu_kernel<<<16384,256,0,stream>>>(ug, mbuf);
    gemm_bt<1><<<8*32,256,0,stream>>>(mbuf, w2T + (size_t)l*1024*4096, x, 4096, 1024, 4096, 8, 32);
  }
  rmsnorm_kernel<0><<<4096,256,0,stream>>>(x, final_nw, d_out);
}

// Round 5
// 709.739 us; speedup vs baseline: 1.5471x; 1.1218x over previous
//
#include <hip/hip_runtime.h>
#include <stdint.h>

typedef __attribute__((ext_vector_type(8))) short s16x8;
typedef __attribute__((ext_vector_type(4))) float f32x4;

#define CB 2
#define CT 2048
#define CD 1024
#define CNH 16
#define CHD 64
#define CDFF 4096
#define CKB 512

__device__ __forceinline__ short f2bf(float f){
  union { float f; uint32_t u; } v; v.f = f;
  uint32_t r = v.u + 0x7FFFu + ((v.u >> 16) & 1u);
  return (short)(r >> 16);
}
__device__ __forceinline__ float bf2f(short h){
  union { uint32_t u; float f; } v; v.u = ((uint32_t)(uint16_t)h) << 16;
  return v.f;
}

#define GLOAD16(g, l) __builtin_amdgcn_global_load_lds( \
    (const __attribute__((address_space(1))) void*)(g), \
    (__attribute__((address_space(3))) void*)(l), 16, 0, 0)

// ---------------- gather + residual ----------------
__global__ void gather_kernel(const float* __restrict__ xp, const int* __restrict__ bnd,
                              const float* __restrict__ xr, float* __restrict__ x){
  int t = blockIdx.x, b = blockIdx.y, tid = threadIdx.x;
  int lo = 0, hi = CKB;
  while (lo < hi){ int mid = (lo + hi) >> 1; if (bnd[b*CKB + mid] <= t) lo = mid + 1; else hi = mid; }
  const float4* s  = (const float4*)(xp + ((size_t)b*CKB + lo)*CD);
  const float4* rr = (const float4*)(xr + ((size_t)b*CT + t)*CD);
  float4* dst      = (float4*)(x  + ((size_t)b*CT + t)*CD);
  float4 a = s[tid], c = rr[tid];
  float4 o; o.x = a.x + c.x; o.y = a.y + c.y; o.z = a.z + c.z; o.w = a.w + c.w;
  dst[tid] = o;
}

// ---------------- weight fp32 -> bf16 transpose ----------------
__global__ void wtrans_kernel(const float* __restrict__ W, short* __restrict__ dst,
                              int Kd, int Nd){
  __shared__ __align__(16) float tile[64*65];
  int n0 = blockIdx.x*64, k0 = blockIdx.y*64;
  #pragma unroll
  for (int i = 0; i < 16; ++i){
    int e = threadIdx.x + 256*i; int kl = e >> 6, nl = e & 63;
    tile[kl*65 + nl] = W[(size_t)(k0 + kl)*Nd + n0 + nl];
  }
  __syncthreads();
  #pragma unroll
  for (int i = 0; i < 16; ++i){
    int e = threadIdx.x + 256*i; int nl = e >> 6, kl = e & 63;
    dst[(size_t)(n0 + nl)*Kd + k0 + kl] = f2bf(tile[kl*65 + nl]);
  }
}

// interleaved variant for w1/w3: dst row = (c/16)*32 + off16 + c%16
__global__ void wtrans_inter_kernel(const float* __restrict__ W, short* __restrict__ dst,
                                    int Kd, int Nd, int off16){
  __shared__ __align__(16) float tile[64*65];
  int n0 = blockIdx.x*64, k0 = blockIdx.y*64;
  #pragma unroll
  for (int i = 0; i < 16; ++i){
    int e = threadIdx.x + 256*i; int kl = e >> 6, nl = e & 63;
    tile[kl*65 + nl] = W[(size_t)(k0 + kl)*Nd + n0 + nl];
  }
  __syncthreads();
  #pragma unroll
  for (int i = 0; i < 16; ++i){
    int e = threadIdx.x + 256*i; int nl = e >> 6, kl = e & 63;
    int c = n0 + nl;
    int frow = ((c >> 4) << 5) + off16 + (c & 15);
    dst[(size_t)frow*Kd + k0 + kl] = f2bf(tile[kl*65 + nl]);
  }
}

// ---------------- RMSNorm ----------------
template<int OUT_BF16>
__global__ void rmsnorm_kernel(const float* __restrict__ x, const float* __restrict__ w,
                               void* __restrict__ outv){
  int row = blockIdx.x, tid = threadIdx.x;
  const float4 xv = ((const float4*)(x + (size_t)row*CD))[tid];
  float ss = xv.x*xv.x + xv.y*xv.y + xv.z*xv.z + xv.w*xv.w;
  #pragma unroll
  for (int m = 1; m < 64; m <<= 1) ss += __shfl_xor(ss, m);
  __shared__ float red[4];
  if ((tid & 63) == 0) red[tid >> 6] = ss;
  __syncthreads();
  float tot = red[0] + red[1] + red[2] + red[3];
  float scale = rsqrtf(tot * (1.0f/1024.0f) + 1e-5f);
  const float4 wv = ((const float4*)w)[tid];
  if (OUT_BF16){
    short4 o;
    o.x = f2bf(xv.x*scale*wv.x); o.y = f2bf(xv.y*scale*wv.y);
    o.z = f2bf(xv.z*scale*wv.z); o.w = f2bf(xv.w*scale*wv.w);
    ((short4*)outv)[(size_t)row*256 + tid] = o;
  } else {
    float4 o;
    o.x = xv.x*scale*wv.x; o.y = xv.y*scale*wv.y;
    o.z = xv.z*scale*wv.z; o.w = xv.w*scale*wv.w;
    ((float4*)outv)[(size_t)row*256 + tid] = o;
  }
}

// ---------------- block-index swizzle (m204 bijective XCD + GM raster) ----------
__device__ __forceinline__ void swz_block_id(int id, int NX, int NY, int& bm, int& bn){
  const int nwg = NX*NY;
  const int qq = nwg >> 3, rr8 = nwg & 7;
  const int xcd = id & 7, loc = id >> 3;
  const int wgid = (xcd < rr8 ? xcd*(qq+1) : rr8*(qq+1) + (xcd-rr8)*qq) + loc;
  const int GM = 8;
  const int gsz = GM * NX;
  const int gidg = wgid / gsz;
  const int remg = wgid - gidg*gsz;
  bm = gidg*GM + (remg % GM);
  bn = remg / GM;
}

// ---------------- GEMM 2-phase 128x128 (WO) ----------------
template<int EPI>
__global__ __launch_bounds__(256) void gemm_bt(const short* __restrict__ A,
                                               const short* __restrict__ Bt,
                                               void* __restrict__ Cv,
                                               int M, int N, int K,
                                               int NX, int NY){
  __shared__ __align__(16) short sA[2][128*32];
  __shared__ __align__(16) short sB[2][128*32];
  const int tid = threadIdx.x;
  const int lane = tid & 63, wid = tid >> 6;
  const int wm = wid >> 1, wn = wid & 1;
  const int lr = lane & 15, lg = lane >> 4;
  int bm, bn; swz_block_id(blockIdx.x, NX, NY, bm, bn);
  const int bm0 = bm * 128, bn0 = bn * 128;

  f32x4 acc[4][4];
  #pragma unroll
  for (int i = 0; i < 4; ++i)
    #pragma unroll
    for (int j = 0; j < 4; ++j) acc[i][j] = (f32x4){0.f,0.f,0.f,0.f};

  const short* gA = A  + (size_t)(bm0 + wid*32 + (lane >> 2))*K + (lane & 3)*8;
  const short* gB = Bt + (size_t)(bn0 + wid*32 + (lane >> 2))*K + (lane & 3)*8;

  #pragma unroll
  for (int iss = 0; iss < 2; ++iss){
    GLOAD16(gA + (size_t)iss*16*K, &sA[0][wid*1024 + iss*16*32]);
    GLOAD16(gB + (size_t)iss*16*K, &sB[0][wid*1024 + iss*16*32]);
  }
  __syncthreads();

  int cur = 0;
  for (int k0 = 0; k0 < K; k0 += 32){
    if (k0 + 32 < K){
      #pragma unroll
      for (int iss = 0; iss < 2; ++iss){
        GLOAD16(gA + (size_t)iss*16*K + k0 + 32, &sA[cur^1][wid*1024 + iss*16*32]);
        GLOAD16(gB + (size_t)iss*16*K + k0 + 32, &sB[cur^1][wid*1024 + iss*16*32]);
      }
    }
    s16x8 af[4], bq[4];
    #pragma unroll
    for (int i = 0; i < 4; ++i) af[i] = *(const s16x8*)&sA[cur][(wm*64 + i*16 + lr)*32 + lg*8];
    #pragma unroll
    for (int j = 0; j < 4; ++j) bq[j] = *(const s16x8*)&sB[cur][(wn*64 + j*16 + lr)*32 + lg*8];
    #pragma unroll
    for (int i = 0; i < 4; ++i)
      #pragma unroll
      for (int j = 0; j < 4; ++j)
        acc[i][j] = __builtin_amdgcn_mfma_f32_16x16x32_bf16(af[i], bq[j], acc[i][j], 0, 0, 0);
    __syncthreads();
    cur ^= 1;
  }

  if (EPI == 0){
    short* C = (short*)Cv;
    #pragma unroll
    for (int i = 0; i < 4; ++i){
      int row0 = bm0 + wm*64 + i*16 + lg*4;
      #pragma unroll
      for (int j = 0; j < 4; ++j){
        int col = bn0 + wn*64 + j*16 + lr;
        #pragma unroll
        for (int r = 0; r < 4; ++r) C[(size_t)(row0 + r)*N + col] = f2bf(acc[i][j][r]);
      }
    }
  } else {
    float* C = (float*)Cv;
    #pragma unroll
    for (int i = 0; i < 4; ++i){
      int row0 = bm0 + wm*64 + i*16 + lg*4;
      #pragma unroll
      for (int j = 0; j < 4; ++j){
        int col = bn0 + wn*64 + j*16 + lr;
        #pragma unroll
        for (int r = 0; r < 4; ++r) C[(size_t)(row0 + r)*N + col] += acc[i][j][r];
      }
    }
  }
}

// ---------------- GEMM split-K 128x128 -> fp32 partials (W2) ----------------
__global__ __launch_bounds__(256) void gemm_splitk(const short* __restrict__ A,
                                                   const short* __restrict__ Bt,
                                                   float* __restrict__ Cp,
                                                   int M, int N, int Ktot, int Kchunk,
                                                   int NX, int NY){
  __shared__ __align__(16) short sA[2][128*32];
  __shared__ __align__(16) short sB[2][128*32];
  const int tid = threadIdx.x;
  const int lane = tid & 63, wid = tid >> 6;
  const int wm = wid >> 1, wn = wid & 1;
  const int lr = lane & 15, lg = lane >> 4;
  const int nin = NX*NY;
  const int split = blockIdx.x / nin;
  const int inner = blockIdx.x - split*nin;
  int bm, bn; swz_block_id(inner, NX, NY, bm, bn);
  const int bm0 = bm * 128, bn0 = bn * 128;
  const int koff = split * Kchunk;

  f32x4 acc[4][4];
  #pragma unroll
  for (int i = 0; i < 4; ++i)
    #pragma unroll
    for (int j = 0; j < 4; ++j) acc[i][j] = (f32x4){0.f,0.f,0.f,0.f};

  const short* gA = A  + (size_t)(bm0 + wid*32 + (lane >> 2))*Ktot + koff + (lane & 3)*8;
  const short* gB = Bt + (size_t)(bn0 + wid*32 + (lane >> 2))*Ktot + koff + (lane & 3)*8;

  #pragma unroll
  for (int iss = 0; iss < 2; ++iss){
    GLOAD16(gA + (size_t)iss*16*Ktot, &sA[0][wid*1024 + iss*16*32]);
    GLOAD16(gB + (size_t)iss*16*Ktot, &sB[0][wid*1024 + iss*16*32]);
  }
  __syncthreads();

  int cur = 0;
  for (int k0 = 0; k0 < Kchunk; k0 += 32){
    if (k0 + 32 < Kchunk){
      #pragma unroll
      for (int iss = 0; iss < 2; ++iss){
        GLOAD16(gA + (size_t)iss*16*Ktot + k0 + 32, &sA[cur^1][wid*1024 + iss*16*32]);
        GLOAD16(gB + (size_t)iss*16*Ktot + k0 + 32, &sB[cur^1][wid*1024 + iss*16*32]);
      }
    }
    s16x8 af[4], bq[4];
    #pragma unroll
    for (int i = 0; i < 4; ++i) af[i] = *(const s16x8*)&sA[cur][(wm*64 + i*16 + lr)*32 + lg*8];
    #pragma unroll
    for (int j = 0; j < 4; ++j) bq[j] = *(const s16x8*)&sB[cur][(wn*64 + j*16 + lr)*32 + lg*8];
    #pragma unroll
    for (int i = 0; i < 4; ++i)
      #pragma unroll
      for (int j = 0; j < 4; ++j)
        acc[i][j] = __builtin_amdgcn_mfma_f32_16x16x32_bf16(af[i], bq[j], acc[i][j], 0, 0, 0);
    __syncthreads();
    cur ^= 1;
  }

  float* C = Cp + (size_t)split*M*N;
  #pragma unroll
  for (int i = 0; i < 4; ++i){
    int row0 = bm0 + wm*64 + i*16 + lg*4;
    #pragma unroll
    for (int j = 0; j < 4; ++j){
      int col = bn0 + wn*64 + j*16 + lr;
      #pragma unroll
      for (int r = 0; r < 4; ++r) C[(size_t)(row0 + r)*N + col] = acc[i][j][r];
    }
  }
}

// x += p0+p1+p2+p3   (4096x1024 fp32)
__global__ void redadd_kernel(float* __restrict__ x, const float* __restrict__ Cp){
  size_t i = (size_t)blockIdx.x*256 + threadIdx.x;
  const float4* p0 = (const float4*)Cp;
  const float4* p1 = p0 + (size_t)1048576;
  const float4* p2 = p1 + (size_t)1048576;
  const float4* p3 = p2 + (size_t)1048576;
  float4 a = ((float4*)x)[i];
  float4 q0 = p0[i], q1 = p1[i], q2 = p2[i], q3 = p3[i];
  a.x += (q0.x + q1.x) + (q2.x + q3.x);
  a.y += (q0.y + q1.y) + (q2.y + q3.y);
  a.z += (q0.z + q1.z) + (q2.z + q3.z);
  a.w += (q0.w + q1.w) + (q2.w + q3.w);
  ((float4*)x)[i] = a;
}

// ---------------- GEMM 8-phase 256x256, BK=64, 8 waves, counted vmcnt ----------
#define STAGE8(u, kt, bufx) do { \
  const short* Gp_ = ((u)&1) ? Bt : A; \
  const int rb_ = ((u)&1) ? bn0 : bm0; \
  const int kh_ = (u)>>1; \
  _Pragma("unroll") \
  for (int L_ = 0; L_ < 2; ++L_){ \
    int rowS_ = L_*128 + wid*16 + (lane>>2); \
    int sp_ = (lane&3) ^ ((rowS_>>1)&3); \
    GLOAD16(Gp_ + (size_t)(rb_ + rowS_)*K + (size_t)(kt)*64 + kh_*32 + sp_*8, \
            &sAB[bufx][u][(L_*512 + wid*64)*8]); \
  } \
} while(0)

#define PHASE8(p, ch, kk) do { \
  if (pf) STAGE8(p, kt+1, nbuf); \
  s16x8 af_[4], bq_[4]; \
  _Pragma("unroll") \
  for (int ii_ = 0; ii_ < 4; ++ii_){ \
    int rowA_ = wm*128 + ((ch)*4 + ii_)*16 + lr; \
    af_[ii_] = *(const s16x8*)&sAB[buf][(kk)*2][rowA_*32 + ((lg ^ ((rowA_>>1)&3))<<3)]; \
  } \
  _Pragma("unroll") \
  for (int j_ = 0; j_ < 4; ++j_){ \
    int rowB_ = wn*64 + j_*16 + lr; \
    bq_[j_] = *(const s16x8*)&sAB[buf][(kk)*2+1][rowB_*32 + ((lg ^ ((rowB_>>1)&3))<<3)]; \
  } \
  __builtin_amdgcn_s_barrier(); \
  asm volatile("s_waitcnt lgkmcnt(0)" ::: "memory"); \
  __builtin_amdgcn_s_setprio(1); \
  _Pragma("unroll") \
  for (int ii_ = 0; ii_ < 4; ++ii_) \
    _Pragma("unroll") \
    for (int j_ = 0; j_ < 4; ++j_) \
      acc[(ch)*4 + ii_][j_] = __builtin_amdgcn_mfma_f32_16x16x32_bf16(af_[ii_], bq_[j_], acc[(ch)*4 + ii_][j_], 0, 0, 0); \
  __builtin_amdgcn_s_setprio(0); \
  if ((p) == 1){ \
    if (pf) asm volatile("s_waitcnt vmcnt(4)" ::: "memory"); \
    else    asm volatile("s_waitcnt vmcnt(0)" ::: "memory"); \
  } \
  if ((p) == 3 && pf) asm volatile("s_waitcnt vmcnt(4)" ::: "memory"); \
  __builtin_amdgcn_s_barrier(); \
} while(0)

// FUSE 0: bf16 C[M,N].  FUSE 1: silu-fused, interleaved u/g cols -> bf16 C[M,N/2].
template<int FUSE>
__global__ __launch_bounds__(512, 2) void gemm8p(const short* __restrict__ A,
                                                 const short* __restrict__ Bt,
                                                 short* __restrict__ C,
                                                 int M, int N, int K,
                                                 int NX, int NY){
  __shared__ __align__(16) short sAB[2][4][256*32];
  const int tid = threadIdx.x;
  const int lane = tid & 63, wid = tid >> 6;
  const int wm = wid >> 2, wn = wid & 3;
  const int lr = lane & 15, lg = lane >> 4;
  int bm, bn; swz_block_id(blockIdx.x, NX, NY, bm, bn);
  const int bm0 = bm * 256, bn0 = bn * 256;

  f32x4 acc[8][4];
  #pragma unroll
  for (int i = 0; i < 8; ++i)
    #pragma unroll
    for (int j = 0; j < 4; ++j) acc[i][j] = (f32x4){0.f,0.f,0.f,0.f};

  const int NK = K >> 6;
  STAGE8(0, 0, 0);
  STAGE8(1, 0, 0);
  STAGE8(2, 0, 0);
  STAGE8(3, 0, 0);
  asm volatile("s_waitcnt vmcnt(4)" ::: "memory");
  __builtin_amdgcn_s_barrier();

  #pragma unroll 1
  for (int kt = 0; kt < NK; ++kt){
    const bool pf = (kt + 1 < NK);
    const int buf = kt & 1, nbuf = buf ^ 1;
    PHASE8(0, 0, 0);
    PHASE8(1, 1, 0);
    PHASE8(2, 0, 1);
    PHASE8(3, 1, 1);
  }

  if (FUSE == 0){
    #pragma unroll
    for (int i = 0; i < 8; ++i){
      int row0 = bm0 + wm*128 + i*16 + lg*4;
      #pragma unroll
      for (int j = 0; j < 4; ++j){
        int col = bn0 + wn*64 + j*16 + lr;
        #pragma unroll
        for (int r = 0; r < 4; ++r) C[(size_t)(row0 + r)*N + col] = f2bf(acc[i][j][r]);
      }
    }
  } else {
    const int Nh = N >> 1;
    #pragma unroll
    for (int i = 0; i < 8; ++i){
      int row0 = bm0 + wm*128 + i*16 + lg*4;
      #pragma unroll
      for (int jp = 0; jp < 2; ++jp){
        int col = (bn0 >> 1) + wn*32 + jp*16 + lr;
        #pragma unroll
        for (int r = 0; r < 4; ++r){
          float u = acc[i][jp*2][r], g = acc[i][jp*2+1][r];
          float val = u / (1.f + __expf(-u)) * g;
          C[(size_t)(row0 + r)*Nh + col] = f2bf(val);
        }
      }
    }
  }
}

// ---------------- RoPE ----------------
__global__ void rope_kernel(const short* __restrict__ qkv, const float* __restrict__ cosb,
                            const float* __restrict__ sinb, short* __restrict__ Qo,
                            short* __restrict__ Ko){
  int g = blockIdx.x*256 + threadIdx.x;
  int d = g & 31;
  int h = (g >> 5) & 15;
  int t = (g >> 9) & 2047;
  int b = g >> 20;
  size_t row = (size_t)b*CT + t;
  const short* src = qkv + row*3072 + h*64;
  float q0 = bf2f(src[d]),        q1 = bf2f(src[d+32]);
  float k0 = bf2f(src[1024+d]),   k1 = bf2f(src[1024+d+32]);
  float c0 = cosb[t*64 + d], c1 = cosb[t*64 + d + 32];
  float s0 = sinb[t*64 + d], s1 = sinb[t*64 + d + 32];
  size_t o = row*CD + h*64;
  const float sc = 0.125f;
  Qo[o + d]      = f2bf((q0*c0 - q1*s0)*sc);
  Qo[o + d + 32] = f2bf((q1*c1 + q0*s1)*sc);
  Ko[o + d]      = f2bf(k0*c0 - k1*s0);
  Ko[o + d + 32] = f2bf(k1*c1 + k0*s1);
}

// ---------------- V transpose ----------------
__global__ void vtrans_kernel(const short* __restrict__ qkv, short* __restrict__ Vt){
  __shared__ __align__(16) short tile[64*65];
  int t0 = blockIdx.x*64;
  int h = blockIdx.y & 15, b = blockIdx.y >> 4;
  #pragma unroll
  for (int i = 0; i < 16; ++i){
    int e = threadIdx.x + 256*i; int tl = e >> 6, d = e & 63;
    tile[tl*65 + d] = qkv[(size_t)(b*CT + t0 + tl)*3072 + 2048 + h*64 + d];
  }
  __syncthreads();
  #pragma unroll
  for (int i = 0; i < 16; ++i){
    int e = threadIdx.x + 256*i; int dl = e >> 6, tl = e & 63;
    Vt[((size_t)(b*CNH + h)*CHD + dl)*CT + t0 + tl] = tile[tl*65 + dl];
  }
}

// ---------------- causal flash attention ----------------
__global__ __launch_bounds__(256) void attn_kernel(const short* __restrict__ Q,
                                                   const short* __restrict__ Kb,
                                                   const short* __restrict__ Vt,
                                                   short* __restrict__ O){
  __shared__ __align__(16) short Kl[64*72];
  __shared__ __align__(16) short Vl[64*72];
  __shared__ __align__(16) short Pl[4][32*72];
  const int tid = threadIdx.x, lane = tid & 63, w = tid >> 6;
  const int qblk = gridDim.x - 1 - blockIdx.x;
  const int h = blockIdx.y, b = blockIdx.z;
  const int lr = lane & 15, lg = lane >> 4;
  const int wq0 = qblk*128 + w*32;

  s16x8 qf[2][2];
  #pragma unroll
  for (int qh = 0; qh < 2; ++qh){
    const short* qp = Q + ((size_t)(b*CT + wq0 + qh*16 + lr)*CNH + h)*CHD + lg*8;
    qf[qh][0] = *(const s16x8*)qp;
    qf[qh][1] = *(const s16x8*)(qp + 32);
  }
  f32x4 oacc[2][4];
  #pragma unroll
  for (int qh = 0; qh < 2; ++qh)
    #pragma unroll
    for (int dt = 0; dt < 4; ++dt) oacc[qh][dt] = (f32x4){0.f,0.f,0.f,0.f};
  float m_r[2] = {-1e30f,-1e30f};
  float l_r[2] = {0.f,0.f};

  const int jmax = 2*qblk + 2;
  const short* gK = Kb + (size_t)b*CT*CD + h*CHD;
  const short* gV = Vt + (size_t)(b*CNH + h)*CHD*CT;
  const int srow0 = tid >> 3, scol = (tid & 7)*8;

  {
    #pragma unroll
    for (int p = 0; p < 2; ++p){
      int row = srow0 + p*32;
      s16x8 k0 = *(const s16x8*)(gK + (size_t)row*CD + scol);
      s16x8 v0 = *(const s16x8*)(gV + (size_t)row*CT + scol);
      *(s16x8*)&Kl[row*72 + scol] = k0;
      *(s16x8*)&Vl[row*72 + scol] = v0;
    }
  }
  __syncthreads();

  for (int j = 0; j < jmax; ++j){
    const int kv0 = j*64;
    s16x8 nk[2], nv[2];
    const bool havenext = (j + 1 < jmax);
    if (havenext){
      const int kv1 = kv0 + 64;
      #pragma unroll
      for (int p = 0; p < 2; ++p){
        int row = srow0 + p*32;
        nk[p] = *(const s16x8*)(gK + (size_t)(kv1 + row)*CD + scol);
        nv[p] = *(const s16x8*)(gV + (size_t)row*CT + kv1 + scol);
      }
    }

    if (kv0 < wq0 + 32){
      f32x4 sc[2][4];
      #pragma unroll
      for (int nt = 0; nt < 4; ++nt){
        s16x8 k0 = *(const s16x8*)&Kl[(nt*16 + lr)*72 + lg*8];
        s16x8 k1 = *(const s16x8*)&Kl[(nt*16 + lr)*72 + 32 + lg*8];
        #pragma unroll
        for (int qh = 0; qh < 2; ++qh){
          f32x4 z = (f32x4){0.f,0.f,0.f,0.f};
          z = __builtin_amdgcn_mfma_f32_16x16x32_bf16(k0, qf[qh][0], z, 0, 0, 0);
          z = __builtin_amdgcn_mfma_f32_16x16x32_bf16(k1, qf[qh][1], z, 0, 0, 0);
          sc[qh][nt] = z;
        }
      }
      if (kv0 + 64 > wq0){
        #pragma unroll
        for (int qh = 0; qh < 2; ++qh)
          #pragma unroll
          for (int nt = 0; nt < 4; ++nt)
            #pragma unroll
            for (int r = 0; r < 4; ++r)
              if (kv0 + nt*16 + lg*4 + r > wq0 + qh*16 + lr) sc[qh][nt][r] = -1e30f;
      }
      #pragma unroll
      for (int qh = 0; qh < 2; ++qh){
        float mx = sc[qh][0][0];
        #pragma unroll
        for (int nt = 0; nt < 4; ++nt)
          #pragma unroll
          for (int r = 0; r < 4; ++r) mx = fmaxf(mx, sc[qh][nt][r]);
        mx = fmaxf(mx, __shfl_xor(mx, 16));
        mx = fmaxf(mx, __shfl_xor(mx, 32));
        float mn = fmaxf(m_r[qh], mx);
        float corr = __expf(m_r[qh] - mn);
        m_r[qh] = mn;
        float rs = 0.f;
        #pragma unroll
        for (int nt = 0; nt < 4; ++nt)
          #pragma unroll
          for (int r = 0; r < 4; ++r){
            float pv = __expf(sc[qh][nt][r] - mn);
            rs += pv;
            Pl[w][(qh*16 + lr)*72 + nt*16 + lg*4 + r] = f2bf(pv);
          }
        rs += __shfl_xor(rs, 16);
        rs += __shfl_xor(rs, 32);
        l_r[qh] = l_r[qh]*corr + rs;
        #pragma unroll
        for (int r = 0; r < 4; ++r){
          float c4 = __shfl(corr, lg*4 + r);
          #pragma unroll
          for (int dt = 0; dt < 4; ++dt) oacc[qh][dt][r] *= c4;
        }
      }
      s16x8 pa[2][2];
      #pragma unroll
      for (int qh = 0; qh < 2; ++qh){
        pa[qh][0] = *(const s16x8*)&Pl[w][(qh*16 + lr)*72 + lg*8];
        pa[qh][1] = *(const s16x8*)&Pl[w][(qh*16 + lr)*72 + 32 + lg*8];
      }
      #pragma unroll
      for (int dt = 0; dt < 4; ++dt){
        s16x8 v0 = *(const s16x8*)&Vl[(dt*16 + lr)*72 + lg*8];
        s16x8 v1 = *(const s16x8*)&Vl[(dt*16 + lr)*72 + 32 + lg*8];
        #pragma unroll
        for (int qh = 0; qh < 2; ++qh){
          oacc[qh][dt] = __builtin_amdgcn_mfma_f32_16x16x32_bf16(pa[qh][0], v0, oacc[qh][dt], 0, 0, 0);
          oacc[qh][dt] = __builtin_amdgcn_mfma_f32_16x16x32_bf16(pa[qh][1], v1, oacc[qh][dt], 0, 0, 0);
        }
      }
    }
    __syncthreads();
    if (havenext){
      #pragma unroll
      for (int p = 0; p < 2; ++p){
        int row = srow0 + p*32;
        *(s16x8*)&Kl[row*72 + scol] = nk[p];
        *(s16x8*)&Vl[row*72 + scol] = nv[p];
      }
    }
    __syncthreads();
  }

  #pragma unroll
  for (int qh = 0; qh < 2; ++qh)
    #pragma unroll
    for (int r = 0; r < 4; ++r){
      float lf = __shfl(l_r[qh], lg*4 + r);
      float inv = 1.f / lf;
      int qrow = wq0 + qh*16 + lg*4 + r;
      #pragma unroll
      for (int dt = 0; dt < 4; ++dt)
        O[((size_t)(b*CT + qrow)*CNH + h)*CHD + dt*16 + lr] = f2bf(oacc[qh][dt][r] * inv);
    }
}

// ---------------- launch ----------------
extern "C" void kernel_launch(void* const* d_in, const int* in_sizes, int n_in,
                              void* d_out, int out_size, void* d_ws, size_t ws_size,
                              hipStream_t stream){
  (void)in_sizes; (void)n_in; (void)out_size; (void)ws_size;
  const float* x_processed = (const float*)d_in[0];
  const int*   boundaries  = (const int*)d_in[1];
  const float* x_residual  = (const float*)d_in[3];
  const float* cosb        = (const float*)d_in[4];
  const float* sinb        = (const float*)d_in[5];
  const float* wq          = (const float*)d_in[7];
  const float* wk          = (const float*)d_in[8];
  const float* wv          = (const float*)d_in[9];
  const float* wo          = (const float*)d_in[10];
  const float* attn_nw     = (const float*)d_in[11];
  const float* mlp_nw      = (const float*)d_in[12];
  const float* w1          = (const float*)d_in[13];
  const float* w3          = (const float*)d_in[14];
  const float* w2          = (const float*)d_in[15];
  const float* final_nw    = (const float*)d_in[16];

  char* p = (char*)d_ws;
  auto alloc = [&](size_t bytes)->char*{
    char* r = p; p += (bytes + 255) & ~(size_t)255; return r;
  };
  short* wqkvT = (short*)alloc((size_t)2*3072*1024*2);
  short* woT   = (short*)alloc((size_t)2*1024*1024*2);
  short* w13T  = (short*)alloc((size_t)2*8192*1024*2);
  short* w2T   = (short*)alloc((size_t)2*1024*4096*2);
  float* x     = (float*)alloc((size_t)4096*1024*4);
  short* hbuf  = (short*)alloc((size_t)4096*1024*2);
  short* qkv   = (short*)alloc((size_t)4096*3072*2);
  short* qr    = (short*)alloc((size_t)4096*1024*2);
  short* kr    = (short*)alloc((size_t)4096*1024*2);
  short* vt    = (short*)alloc((size_t)4096*1024*2);
  short* obuf  = (short*)alloc((size_t)4096*1024*2);
  short* mbuf  = (short*)alloc((size_t)4096*4096*2);
  float* psum  = (float*)alloc((size_t)4*4096*1024*4);

  for (int l = 0; l < 2; ++l){
    size_t wOff = (size_t)l*1024*1024;
    wtrans_kernel<<<dim3(16,16),256,0,stream>>>(wq + wOff, wqkvT + (size_t)l*3072*1024,                     1024, 1024);
    wtrans_kernel<<<dim3(16,16),256,0,stream>>>(wk + wOff, wqkvT + (size_t)l*3072*1024 + (size_t)1024*1024, 1024, 1024);
    wtrans_kernel<<<dim3(16,16),256,0,stream>>>(wv + wOff, wqkvT + (size_t)l*3072*1024 + (size_t)2048*1024, 1024, 1024);
    wtrans_kernel<<<dim3(16,16),256,0,stream>>>(wo + wOff, woT + (size_t)l*1024*1024,                       1024, 1024);
    wtrans_inter_kernel<<<dim3(64,16),256,0,stream>>>(w1 + (size_t)l*1024*4096, w13T + (size_t)l*8192*1024, 1024, 4096, 0);
    wtrans_inter_kernel<<<dim3(64,16),256,0,stream>>>(w3 + (size_t)l*1024*4096, w13T + (size_t)l*8192*1024, 1024, 4096, 16);
    wtrans_kernel<<<dim3(16,64),256,0,stream>>>(w2 + (size_t)l*4096*1024, w2T + (size_t)l*1024*4096,        4096, 1024);
  }
  gather_kernel<<<dim3(2048,2),256,0,stream>>>(x_processed, boundaries, x_residual, x);
  for (int l = 0; l < 2; ++l){
    rmsnorm_kernel<1><<<4096,256,0,stream>>>(x, attn_nw + l*1024, hbuf);
    gemm8p<0><<<12*16,512,0,stream>>>(hbuf, wqkvT + (size_t)l*3072*1024, qkv, 4096, 3072, 1024, 12, 16);
    rope_kernel<<<8192,256,0,stream>>>(qkv, cosb, sinb, qr, kr);
    vtrans_kernel<<<dim3(32,32),256,0,stream>>>(qkv, vt);
    attn_kernel<<<dim3(16,16,2),256,0,stream>>>(qr, kr, vt, obuf);
    gemm_bt<1><<<8*32,256,0,stream>>>(obuf, woT + (size_t)l*1024*1024, x, 4096, 1024, 1024, 8, 32);
    rmsnorm_kernel<1><<<4096,256,0,stream>>>(x, mlp_nw + l*1024, hbuf);
    gemm8p<1><<<32*16,512,0,stream>>>(hbuf, w13T + (size_t)l*8192*1024, mbuf, 4096, 8192, 1024, 32, 16);
    gemm_splitk<<<8*32*4,256,0,stream>>>(mbuf, w2T + (size_t)l*1024*4096, psum, 4096, 1024, 4096, 1024, 8, 32);
    redadd_kernel<<<4096,256,0,stream>>>(x, psum);
  }
  rmsnorm_kernel<0><<<4096,256,0,stream>>>(x, final_nw, d_out);
}

// Round 6
// 646.352 us; speedup vs baseline: 1.6989x; 1.0981x over previous
//
#include <hip/hip_runtime.h>
#include <stdint.h>

typedef __attribute__((ext_vector_type(8))) short s16x8;
typedef __attribute__((ext_vector_type(4))) float f32x4;

#define CB 2
#define CT 2048
#define CD 1024
#define CNH 16
#define CHD 64
#define CDFF 4096
#define CKB 512

__device__ __forceinline__ short f2bf(float f){
  union { float f; uint32_t u; } v; v.f = f;
  uint32_t r = v.u + 0x7FFFu + ((v.u >> 16) & 1u);
  return (short)(r >> 16);
}
__device__ __forceinline__ float bf2f(short h){
  union { uint32_t u; float f; } v; v.u = ((uint32_t)(uint16_t)h) << 16;
  return v.f;
}
__device__ __forceinline__ uint32_t cvtpk_bf16(float lo, float hi){
  uint32_t r;
  asm("v_cvt_pk_bf16_f32 %0, %1, %2" : "=v"(r) : "v"(lo), "v"(hi));
  return r;
}

#define GLOAD16(g, l) __builtin_amdgcn_global_load_lds( \
    (const __attribute__((address_space(1))) void*)(g), \
    (__attribute__((address_space(3))) void*)(l), 16, 0, 0)

// ---------------- gather + residual ----------------
__global__ void gather_kernel(const float* __restrict__ xp, const int* __restrict__ bnd,
                              const float* __restrict__ xr, float* __restrict__ x){
  int t = blockIdx.x, b = blockIdx.y, tid = threadIdx.x;
  int lo = 0, hi = CKB;
  while (lo < hi){ int mid = (lo + hi) >> 1; if (bnd[b*CKB + mid] <= t) lo = mid + 1; else hi = mid; }
  const float4* s  = (const float4*)(xp + ((size_t)b*CKB + lo)*CD);
  const float4* rr = (const float4*)(xr + ((size_t)b*CT + t)*CD);
  float4* dst      = (float4*)(x  + ((size_t)b*CT + t)*CD);
  float4 a = s[tid], c = rr[tid];
  float4 o; o.x = a.x + c.x; o.y = a.y + c.y; o.z = a.z + c.z; o.w = a.w + c.w;
  dst[tid] = o;
}

// ---------------- weight fp32 -> bf16 transpose ----------------
__global__ void wtrans_kernel(const float* __restrict__ W, short* __restrict__ dst,
                              int Kd, int Nd){
  __shared__ __align__(16) float tile[64*65];
  int n0 = blockIdx.x*64, k0 = blockIdx.y*64;
  #pragma unroll
  for (int i = 0; i < 16; ++i){
    int e = threadIdx.x + 256*i; int kl = e >> 6, nl = e & 63;
    tile[kl*65 + nl] = W[(size_t)(k0 + kl)*Nd + n0 + nl];
  }
  __syncthreads();
  #pragma unroll
  for (int i = 0; i < 16; ++i){
    int e = threadIdx.x + 256*i; int nl = e >> 6, kl = e & 63;
    dst[(size_t)(n0 + nl)*Kd + k0 + kl] = f2bf(tile[kl*65 + nl]);
  }
}

// interleaved variant for w1/w3: dst row = (c/16)*32 + off16 + c%16
__global__ void wtrans_inter_kernel(const float* __restrict__ W, short* __restrict__ dst,
                                    int Kd, int Nd, int off16){
  __shared__ __align__(16) float tile[64*65];
  int n0 = blockIdx.x*64, k0 = blockIdx.y*64;
  #pragma unroll
  for (int i = 0; i < 16; ++i){
    int e = threadIdx.x + 256*i; int kl = e >> 6, nl = e & 63;
    tile[kl*65 + nl] = W[(size_t)(k0 + kl)*Nd + n0 + nl];
  }
  __syncthreads();
  #pragma unroll
  for (int i = 0; i < 16; ++i){
    int e = threadIdx.x + 256*i; int nl = e >> 6, kl = e & 63;
    int c = n0 + nl;
    int frow = ((c >> 4) << 5) + off16 + (c & 15);
    dst[(size_t)frow*Kd + k0 + kl] = f2bf(tile[kl*65 + nl]);
  }
}

// ---------------- RMSNorm ----------------
template<int OUT_BF16>
__global__ void rmsnorm_kernel(const float* __restrict__ x, const float* __restrict__ w,
                               void* __restrict__ outv){
  int row = blockIdx.x, tid = threadIdx.x;
  const float4 xv = ((const float4*)(x + (size_t)row*CD))[tid];
  float ss = xv.x*xv.x + xv.y*xv.y + xv.z*xv.z + xv.w*xv.w;
  #pragma unroll
  for (int m = 1; m < 64; m <<= 1) ss += __shfl_xor(ss, m);
  __shared__ float red[4];
  if ((tid & 63) == 0) red[tid >> 6] = ss;
  __syncthreads();
  float tot = red[0] + red[1] + red[2] + red[3];
  float scale = rsqrtf(tot * (1.0f/1024.0f) + 1e-5f);
  const float4 wv = ((const float4*)w)[tid];
  if (OUT_BF16){
    short4 o;
    o.x = f2bf(xv.x*scale*wv.x); o.y = f2bf(xv.y*scale*wv.y);
    o.z = f2bf(xv.z*scale*wv.z); o.w = f2bf(xv.w*scale*wv.w);
    ((short4*)outv)[(size_t)row*256 + tid] = o;
  } else {
    float4 o;
    o.x = xv.x*scale*wv.x; o.y = xv.y*scale*wv.y;
    o.z = xv.z*scale*wv.z; o.w = xv.w*scale*wv.w;
    ((float4*)outv)[(size_t)row*256 + tid] = o;
  }
}

// ---------------- block-index swizzle (m204 bijective XCD + GM raster) ----------
__device__ __forceinline__ void swz_block_id(int id, int NX, int NY, int& bm, int& bn){
  const int nwg = NX*NY;
  const int qq = nwg >> 3, rr8 = nwg & 7;
  const int xcd = id & 7, loc = id >> 3;
  const int wgid = (xcd < rr8 ? xcd*(qq+1) : rr8*(qq+1) + (xcd-rr8)*qq) + loc;
  const int GM = 8;
  const int gsz = GM * NX;
  const int gidg = wgid / gsz;
  const int remg = wgid - gidg*gsz;
  bm = gidg*GM + (remg % GM);
  bn = remg / GM;
}

// ---------------- GEMM 2-phase 128x128 (WO) ----------------
template<int EPI>
__global__ __launch_bounds__(256) void gemm_bt(const short* __restrict__ A,
                                               const short* __restrict__ Bt,
                                               void* __restrict__ Cv,
                                               int M, int N, int K,
                                               int NX, int NY){
  __shared__ __align__(16) short sA[2][128*32];
  __shared__ __align__(16) short sB[2][128*32];
  const int tid = threadIdx.x;
  const int lane = tid & 63, wid = tid >> 6;
  const int wm = wid >> 1, wn = wid & 1;
  const int lr = lane & 15, lg = lane >> 4;
  int bm, bn; swz_block_id(blockIdx.x, NX, NY, bm, bn);
  const int bm0 = bm * 128, bn0 = bn * 128;

  f32x4 acc[4][4];
  #pragma unroll
  for (int i = 0; i < 4; ++i)
    #pragma unroll
    for (int j = 0; j < 4; ++j) acc[i][j] = (f32x4){0.f,0.f,0.f,0.f};

  const short* gA = A  + (size_t)(bm0 + wid*32 + (lane >> 2))*K + (lane & 3)*8;
  const short* gB = Bt + (size_t)(bn0 + wid*32 + (lane >> 2))*K + (lane & 3)*8;

  #pragma unroll
  for (int iss = 0; iss < 2; ++iss){
    GLOAD16(gA + (size_t)iss*16*K, &sA[0][wid*1024 + iss*16*32]);
    GLOAD16(gB + (size_t)iss*16*K, &sB[0][wid*1024 + iss*16*32]);
  }
  __syncthreads();

  int cur = 0;
  for (int k0 = 0; k0 < K; k0 += 32){
    if (k0 + 32 < K){
      #pragma unroll
      for (int iss = 0; iss < 2; ++iss){
        GLOAD16(gA + (size_t)iss*16*K + k0 + 32, &sA[cur^1][wid*1024 + iss*16*32]);
        GLOAD16(gB + (size_t)iss*16*K + k0 + 32, &sB[cur^1][wid*1024 + iss*16*32]);
      }
    }
    s16x8 af[4], bq[4];
    #pragma unroll
    for (int i = 0; i < 4; ++i) af[i] = *(const s16x8*)&sA[cur][(wm*64 + i*16 + lr)*32 + lg*8];
    #pragma unroll
    for (int j = 0; j < 4; ++j) bq[j] = *(const s16x8*)&sB[cur][(wn*64 + j*16 + lr)*32 + lg*8];
    #pragma unroll
    for (int i = 0; i < 4; ++i)
      #pragma unroll
      for (int j = 0; j < 4; ++j)
        acc[i][j] = __builtin_amdgcn_mfma_f32_16x16x32_bf16(af[i], bq[j], acc[i][j], 0, 0, 0);
    __syncthreads();
    cur ^= 1;
  }

  if (EPI == 0){
    short* C = (short*)Cv;
    #pragma unroll
    for (int i = 0; i < 4; ++i){
      int row0 = bm0 + wm*64 + i*16 + lg*4;
      #pragma unroll
      for (int j = 0; j < 4; ++j){
        int col = bn0 + wn*64 + j*16 + lr;
        #pragma unroll
        for (int r = 0; r < 4; ++r) C[(size_t)(row0 + r)*N + col] = f2bf(acc[i][j][r]);
      }
    }
  } else {
    float* C = (float*)Cv;
    #pragma unroll
    for (int i = 0; i < 4; ++i){
      int row0 = bm0 + wm*64 + i*16 + lg*4;
      #pragma unroll
      for (int j = 0; j < 4; ++j){
        int col = bn0 + wn*64 + j*16 + lr;
        #pragma unroll
        for (int r = 0; r < 4; ++r) C[(size_t)(row0 + r)*N + col] += acc[i][j][r];
      }
    }
  }
}

// ---------------- GEMM split-K 128x128 -> fp32 partials (W2) ----------------
__global__ __launch_bounds__(256) void gemm_splitk(const short* __restrict__ A,
                                                   const short* __restrict__ Bt,
                                                   float* __restrict__ Cp,
                                                   int M, int N, int Ktot, int Kchunk,
                                                   int NX, int NY){
  __shared__ __align__(16) short sA[2][128*32];
  __shared__ __align__(16) short sB[2][128*32];
  const int tid = threadIdx.x;
  const int lane = tid & 63, wid = tid >> 6;
  const int wm = wid >> 1, wn = wid & 1;
  const int lr = lane & 15, lg = lane >> 4;
  const int nin = NX*NY;
  const int split = blockIdx.x / nin;
  const int inner = blockIdx.x - split*nin;
  int bm, bn; swz_block_id(inner, NX, NY, bm, bn);
  const int bm0 = bm * 128, bn0 = bn * 128;
  const int koff = split * Kchunk;

  f32x4 acc[4][4];
  #pragma unroll
  for (int i = 0; i < 4; ++i)
    #pragma unroll
    for (int j = 0; j < 4; ++j) acc[i][j] = (f32x4){0.f,0.f,0.f,0.f};

  const short* gA = A  + (size_t)(bm0 + wid*32 + (lane >> 2))*Ktot + koff + (lane & 3)*8;
  const short* gB = Bt + (size_t)(bn0 + wid*32 + (lane >> 2))*Ktot + koff + (lane & 3)*8;

  #pragma unroll
  for (int iss = 0; iss < 2; ++iss){
    GLOAD16(gA + (size_t)iss*16*Ktot, &sA[0][wid*1024 + iss*16*32]);
    GLOAD16(gB + (size_t)iss*16*Ktot, &sB[0][wid*1024 + iss*16*32]);
  }
  __syncthreads();

  int cur = 0;
  for (int k0 = 0; k0 < Kchunk; k0 += 32){
    if (k0 + 32 < Kchunk){
      #pragma unroll
      for (int iss = 0; iss < 2; ++iss){
        GLOAD16(gA + (size_t)iss*16*Ktot + k0 + 32, &sA[cur^1][wid*1024 + iss*16*32]);
        GLOAD16(gB + (size_t)iss*16*Ktot + k0 + 32, &sB[cur^1][wid*1024 + iss*16*32]);
      }
    }
    s16x8 af[4], bq[4];
    #pragma unroll
    for (int i = 0; i < 4; ++i) af[i] = *(const s16x8*)&sA[cur][(wm*64 + i*16 + lr)*32 + lg*8];
    #pragma unroll
    for (int j = 0; j < 4; ++j) bq[j] = *(const s16x8*)&sB[cur][(wn*64 + j*16 + lr)*32 + lg*8];
    #pragma unroll
    for (int i = 0; i < 4; ++i)
      #pragma unroll
      for (int j = 0; j < 4; ++j)
        acc[i][j] = __builtin_amdgcn_mfma_f32_16x16x32_bf16(af[i], bq[j], acc[i][j], 0, 0, 0);
    __syncthreads();
    cur ^= 1;
  }

  float* C = Cp + (size_t)split*M*N;
  #pragma unroll
  for (int i = 0; i < 4; ++i){
    int row0 = bm0 + wm*64 + i*16 + lg*4;
    #pragma unroll
    for (int j = 0; j < 4; ++j){
      int col = bn0 + wn*64 + j*16 + lr;
      #pragma unroll
      for (int r = 0; r < 4; ++r) C[(size_t)(row0 + r)*N + col] = acc[i][j][r];
    }
  }
}

// x += p0+p1+p2+p3   (4096x1024 fp32)
__global__ void redadd_kernel(float* __restrict__ x, const float* __restrict__ Cp){
  size_t i = (size_t)blockIdx.x*256 + threadIdx.x;
  const float4* p0 = (const float4*)Cp;
  const float4* p1 = p0 + (size_t)1048576;
  const float4* p2 = p1 + (size_t)1048576;
  const float4* p3 = p2 + (size_t)1048576;
  float4 a = ((float4*)x)[i];
  float4 q0 = p0[i], q1 = p1[i], q2 = p2[i], q3 = p3[i];
  a.x += (q0.x + q1.x) + (q2.x + q3.x);
  a.y += (q0.y + q1.y) + (q2.y + q3.y);
  a.z += (q0.z + q1.z) + (q2.z + q3.z);
  a.w += (q0.w + q1.w) + (q2.w + q3.w);
  ((float4*)x)[i] = a;
}

// ---------------- GEMM 8-phase 256x256, BK=64, 8 waves, counted vmcnt ----------
#define STAGE8(u, kt, bufx) do { \
  const short* Gp_ = ((u)&1) ? Bt : A; \
  const int rb_ = ((u)&1) ? bn0 : bm0; \
  const int kh_ = (u)>>1; \
  _Pragma("unroll") \
  for (int L_ = 0; L_ < 2; ++L_){ \
    int rowS_ = L_*128 + wid*16 + (lane>>2); \
    int sp_ = (lane&3) ^ ((rowS_>>1)&3); \
    GLOAD16(Gp_ + (size_t)(rb_ + rowS_)*K + (size_t)(kt)*64 + kh_*32 + sp_*8, \
            &sAB[bufx][u][(L_*512 + wid*64)*8]); \
  } \
} while(0)

#define PHASE8(p, ch, kk) do { \
  if (pf) STAGE8(p, kt+1, nbuf); \
  s16x8 af_[4], bq_[4]; \
  _Pragma("unroll") \
  for (int ii_ = 0; ii_ < 4; ++ii_){ \
    int rowA_ = wm*128 + ((ch)*4 + ii_)*16 + lr; \
    af_[ii_] = *(const s16x8*)&sAB[buf][(kk)*2][rowA_*32 + ((lg ^ ((rowA_>>1)&3))<<3)]; \
  } \
  _Pragma("unroll") \
  for (int j_ = 0; j_ < 4; ++j_){ \
    int rowB_ = wn*64 + j_*16 + lr; \
    bq_[j_] = *(const s16x8*)&sAB[buf][(kk)*2+1][rowB_*32 + ((lg ^ ((rowB_>>1)&3))<<3)]; \
  } \
  __builtin_amdgcn_s_barrier(); \
  asm volatile("s_waitcnt lgkmcnt(0)" ::: "memory"); \
  __builtin_amdgcn_s_setprio(1); \
  _Pragma("unroll") \
  for (int ii_ = 0; ii_ < 4; ++ii_) \
    _Pragma("unroll") \
    for (int j_ = 0; j_ < 4; ++j_) \
      acc[(ch)*4 + ii_][j_] = __builtin_amdgcn_mfma_f32_16x16x32_bf16(af_[ii_], bq_[j_], acc[(ch)*4 + ii_][j_], 0, 0, 0); \
  __builtin_amdgcn_s_setprio(0); \
  if ((p) == 1){ \
    if (pf) asm volatile("s_waitcnt vmcnt(4)" ::: "memory"); \
    else    asm volatile("s_waitcnt vmcnt(0)" ::: "memory"); \
  } \
  if ((p) == 3 && pf) asm volatile("s_waitcnt vmcnt(4)" ::: "memory"); \
  __builtin_amdgcn_s_barrier(); \
} while(0)

// FUSE 0: bf16 C[M,N].  FUSE 1: silu-fused, interleaved u/g cols -> bf16 C[M,N/2].
template<int FUSE>
__global__ __launch_bounds__(512, 2) void gemm8p(const short* __restrict__ A,
                                                 const short* __restrict__ Bt,
                                                 short* __restrict__ C,
                                                 int M, int N, int K,
                                                 int NX, int NY){
  __shared__ __align__(16) short sAB[2][4][256*32];
  const int tid = threadIdx.x;
  const int lane = tid & 63, wid = tid >> 6;
  const int wm = wid >> 2, wn = wid & 3;
  const int lr = lane & 15, lg = lane >> 4;
  int bm, bn; swz_block_id(blockIdx.x, NX, NY, bm, bn);
  const int bm0 = bm * 256, bn0 = bn * 256;

  f32x4 acc[8][4];
  #pragma unroll
  for (int i = 0; i < 8; ++i)
    #pragma unroll
    for (int j = 0; j < 4; ++j) acc[i][j] = (f32x4){0.f,0.f,0.f,0.f};

  const int NK = K >> 6;
  STAGE8(0, 0, 0);
  STAGE8(1, 0, 0);
  STAGE8(2, 0, 0);
  STAGE8(3, 0, 0);
  asm volatile("s_waitcnt vmcnt(4)" ::: "memory");
  __builtin_amdgcn_s_barrier();

  #pragma unroll 1
  for (int kt = 0; kt < NK; ++kt){
    const bool pf = (kt + 1 < NK);
    const int buf = kt & 1, nbuf = buf ^ 1;
    PHASE8(0, 0, 0);
    PHASE8(1, 1, 0);
    PHASE8(2, 0, 1);
    PHASE8(3, 1, 1);
  }

  if (FUSE == 0){
    #pragma unroll
    for (int i = 0; i < 8; ++i){
      int row0 = bm0 + wm*128 + i*16 + lg*4;
      #pragma unroll
      for (int j = 0; j < 4; ++j){
        int col = bn0 + wn*64 + j*16 + lr;
        #pragma unroll
        for (int r = 0; r < 4; ++r) C[(size_t)(row0 + r)*N + col] = f2bf(acc[i][j][r]);
      }
    }
  } else {
    const int Nh = N >> 1;
    #pragma unroll
    for (int i = 0; i < 8; ++i){
      int row0 = bm0 + wm*128 + i*16 + lg*4;
      #pragma unroll
      for (int jp = 0; jp < 2; ++jp){
        int col = (bn0 >> 1) + wn*32 + jp*16 + lr;
        #pragma unroll
        for (int r = 0; r < 4; ++r){
          float u = acc[i][jp*2][r], g = acc[i][jp*2+1][r];
          float val = u / (1.f + __expf(-u)) * g;
          C[(size_t)(row0 + r)*Nh + col] = f2bf(val);
        }
      }
    }
  }
}

// ---------------- RoPE (q scaled by 0.125*log2e for exp2-domain softmax) -------
__global__ void rope_kernel(const short* __restrict__ qkv, const float* __restrict__ cosb,
                            const float* __restrict__ sinb, short* __restrict__ Qo,
                            short* __restrict__ Ko){
  int g = blockIdx.x*256 + threadIdx.x;
  int d = g & 31;
  int h = (g >> 5) & 15;
  int t = (g >> 9) & 2047;
  int b = g >> 20;
  size_t row = (size_t)b*CT + t;
  const short* src = qkv + row*3072 + h*64;
  float q0 = bf2f(src[d]),        q1 = bf2f(src[d+32]);
  float k0 = bf2f(src[1024+d]),   k1 = bf2f(src[1024+d+32]);
  float c0 = cosb[t*64 + d], c1 = cosb[t*64 + d + 32];
  float s0 = sinb[t*64 + d], s1 = sinb[t*64 + d + 32];
  size_t o = row*CD + h*64;
  const float sc = 0.125f * 1.44269504088896340736f;
  Qo[o + d]      = f2bf((q0*c0 - q1*s0)*sc);
  Qo[o + d + 32] = f2bf((q1*c1 + q0*s1)*sc);
  Ko[o + d]      = f2bf(k0*c0 - k1*s0);
  Ko[o + d + 32] = f2bf(k1*c1 + k0*s1);
}

// ---------------- V transpose ----------------
__global__ void vtrans_kernel(const short* __restrict__ qkv, short* __restrict__ Vt){
  __shared__ __align__(16) short tile[64*65];
  int t0 = blockIdx.x*64;
  int h = blockIdx.y & 15, b = blockIdx.y >> 4;
  #pragma unroll
  for (int i = 0; i < 16; ++i){
    int e = threadIdx.x + 256*i; int tl = e >> 6, d = e & 63;
    tile[tl*65 + d] = qkv[(size_t)(b*CT + t0 + tl)*3072 + 2048 + h*64 + d];
  }
  __syncthreads();
  #pragma unroll
  for (int i = 0; i < 16; ++i){
    int e = threadIdx.x + 256*i; int dl = e >> 6, tl = e & 63;
    Vt[((size_t)(b*CNH + h)*CHD + dl)*CT + t0 + tl] = tile[tl*65 + dl];
  }
}

// ---------------- causal flash attention v3 ----------------
// QBLK=64 (4 waves x 16 q-rows), paired q-tiles {31-bx, bx} for uniform work,
// double-buffered K/V LDS (1 barrier/iter), exp2-domain softmax, cvt_pk P-pack,
// defer-max rescale, setprio around MFMA.
__global__ __launch_bounds__(256) void attn_kernel(const short* __restrict__ Q,
                                                   const short* __restrict__ Kb,
                                                   const short* __restrict__ Vt,
                                                   short* __restrict__ O){
  __shared__ __align__(16) short Kl[2][64*72];
  __shared__ __align__(16) short Vl[2][64*72];
  __shared__ __align__(16) short Pl[4][16*72];
  const int tid = threadIdx.x, lane = tid & 63, w = tid >> 6;
  const int qpair = blockIdx.x;          // 0..15
  const int h = blockIdx.y, b = blockIdx.z;
  const int lr = lane & 15, lg = lane >> 4;

  const short* gK = Kb + (size_t)b*CT*CD + h*CHD;
  const short* gV = Vt + (size_t)(b*CNH + h)*CHD*CT;
  const int srow0 = tid >> 3, scol = (tid & 7)*8;

  #pragma unroll 1
  for (int half = 0; half < 2; ++half){
    const int qt = half ? qpair : (31 - qpair);
    const int wq0 = qt*64 + w*16;
    const int jmax = qt + 1;

    s16x8 qf0, qf1;
    {
      const short* qp = Q + ((size_t)(b*CT + wq0 + lr)*CNH + h)*CHD + lg*8;
      qf0 = *(const s16x8*)qp;
      qf1 = *(const s16x8*)(qp + 32);
    }
    f32x4 oacc[4];
    #pragma unroll
    for (int dt = 0; dt < 4; ++dt) oacc[dt] = (f32x4){0.f,0.f,0.f,0.f};
    float m_r = -1e30f, l_r = 0.f;

    // stage tile 0 into buf 0
    #pragma unroll
    for (int p = 0; p < 2; ++p){
      int row = srow0 + p*32;
      *(s16x8*)&Kl[0][row*72 + scol] = *(const s16x8*)(gK + (size_t)row*CD + scol);
      *(s16x8*)&Vl[0][row*72 + scol] = *(const s16x8*)(gV + (size_t)row*CT + scol);
    }
    __syncthreads();

    #pragma unroll 1
    for (int j = 0; j < jmax; ++j){
      const int kv0 = j*64;
      const int buf = j & 1;
      s16x8 nk[2], nv[2];
      const bool havenext = (j + 1 < jmax);
      if (havenext){
        const int kv1 = kv0 + 64;
        #pragma unroll
        for (int p = 0; p < 2; ++p){
          int row = srow0 + p*32;
          nk[p] = *(const s16x8*)(gK + (size_t)(kv1 + row)*CD + scol);
          nv[p] = *(const s16x8*)(gV + (size_t)row*CT + kv1 + scol);
        }
      }

      if (kv0 < wq0 + 16){
        f32x4 sc[4];
        __builtin_amdgcn_s_setprio(1);
        #pragma unroll
        for (int nt = 0; nt < 4; ++nt){
          s16x8 k0 = *(const s16x8*)&Kl[buf][(nt*16 + lr)*72 + lg*8];
          s16x8 k1 = *(const s16x8*)&Kl[buf][(nt*16 + lr)*72 + 32 + lg*8];
          f32x4 z = (f32x4){0.f,0.f,0.f,0.f};
          z = __builtin_amdgcn_mfma_f32_16x16x32_bf16(k0, qf0, z, 0, 0, 0);
          z = __builtin_amdgcn_mfma_f32_16x16x32_bf16(k1, qf1, z, 0, 0, 0);
          sc[nt] = z;
        }
        __builtin_amdgcn_s_setprio(0);
        if (kv0 + 64 > wq0){
          #pragma unroll
          for (int nt = 0; nt < 4; ++nt)
            #pragma unroll
            for (int r = 0; r < 4; ++r)
              if (kv0 + nt*16 + lg*4 + r > wq0 + lr) sc[nt][r] = -1e30f;
        }
        // row max (per-lane 16 values + 2 cross-lane steps over lg)
        float pmax = sc[0][0];
        #pragma unroll
        for (int nt = 0; nt < 4; ++nt)
          #pragma unroll
          for (int r = 0; r < 4; ++r) pmax = fmaxf(pmax, sc[nt][r]);
        pmax = fmaxf(pmax, __shfl_xor(pmax, 16));
        pmax = fmaxf(pmax, __shfl_xor(pmax, 32));
        // defer-max: only rescale when max grew by > 2^10
        if (!__all(pmax - m_r <= 10.f)){
          float mn = fmaxf(m_r, pmax);
          float corr = __builtin_amdgcn_exp2f(m_r - mn);
          m_r = mn;
          l_r *= corr;
          #pragma unroll
          for (int r = 0; r < 4; ++r){
            float c4 = __shfl(corr, lg*4 + r);
            #pragma unroll
            for (int dt = 0; dt < 4; ++dt) oacc[dt][r] *= c4;
          }
        }
        float rs = 0.f;
        #pragma unroll
        for (int nt = 0; nt < 4; ++nt)
          #pragma unroll
          for (int r = 0; r < 4; ++r){
            float pv = __builtin_amdgcn_exp2f(sc[nt][r] - m_r);
            sc[nt][r] = pv;
            rs += pv;
          }
        #pragma unroll
        for (int nt = 0; nt < 4; ++nt){
          uint2 pk;
          pk.x = cvtpk_bf16(sc[nt][0], sc[nt][1]);
          pk.y = cvtpk_bf16(sc[nt][2], sc[nt][3]);
          *(uint2*)&Pl[w][lr*72 + nt*16 + lg*4] = pk;
        }
        rs += __shfl_xor(rs, 16);
        rs += __shfl_xor(rs, 32);
        l_r += rs;
        s16x8 pa0 = *(const s16x8*)&Pl[w][lr*72 + lg*8];
        s16x8 pa1 = *(const s16x8*)&Pl[w][lr*72 + 32 + lg*8];
        __builtin_amdgcn_s_setprio(1);
        #pragma unroll
        for (int dt = 0; dt < 4; ++dt){
          s16x8 v0 = *(const s16x8*)&Vl[buf][(dt*16 + lr)*72 + lg*8];
          s16x8 v1 = *(const s16x8*)&Vl[buf][(dt*16 + lr)*72 + 32 + lg*8];
          oacc[dt] = __builtin_amdgcn_mfma_f32_16x16x32_bf16(pa0, v0, oacc[dt], 0, 0, 0);
          oacc[dt] = __builtin_amdgcn_mfma_f32_16x16x32_bf16(pa1, v1, oacc[dt], 0, 0, 0);
        }
        __builtin_amdgcn_s_setprio(0);
      }
      if (havenext){
        #pragma unroll
        for (int p = 0; p < 2; ++p){
          int row = srow0 + p*32;
          *(s16x8*)&Kl[buf^1][row*72 + scol] = nk[p];
          *(s16x8*)&Vl[buf^1][row*72 + scol] = nv[p];
        }
      }
      __syncthreads();
    }

    #pragma unroll
    for (int r = 0; r < 4; ++r){
      float lf = __shfl(l_r, lg*4 + r);
      float inv = 1.f / lf;
      int qrow = wq0 + lg*4 + r;
      #pragma unroll
      for (int dt = 0; dt < 4; ++dt)
        O[((size_t)(b*CT + qrow)*CNH + h)*CHD + dt*16 + lr] = f2bf(oacc[dt][r] * inv);
    }
  }
}

// ---------------- launch ----------------
extern "C" void kernel_launch(void* const* d_in, const int* in_sizes, int n_in,
                              void* d_out, int out_size, void* d_ws, size_t ws_size,
                              hipStream_t stream){
  (void)in_sizes; (void)n_in; (void)out_size; (void)ws_size;
  const float* x_processed = (const float*)d_in[0];
  const int*   boundaries  = (const int*)d_in[1];
  const float* x_residual  = (const float*)d_in[3];
  const float* cosb        = (const float*)d_in[4];
  const float* sinb        = (const float*)d_in[5];
  const float* wq          = (const float*)d_in[7];
  const float* wk          = (const float*)d_in[8];
  const float* wv          = (const float*)d_in[9];
  const float* wo          = (const float*)d_in[10];
  const float* attn_nw     = (const float*)d_in[11];
  const float* mlp_nw      = (const float*)d_in[12];
  const float* w1          = (const float*)d_in[13];
  const float* w3          = (const float*)d_in[14];
  const float* w2          = (const float*)d_in[15];
  const float* final_nw    = (const float*)d_in[16];

  char* p = (char*)d_ws;
  auto alloc = [&](size_t bytes)->char*{
    char* r = p; p += (bytes + 255) & ~(size_t)255; return r;
  };
  short* wqkvT = (short*)alloc((size_t)2*3072*1024*2);
  short* woT   = (short*)alloc((size_t)2*1024*1024*2);
  short* w13T  = (short*)alloc((size_t)2*8192*1024*2);
  short* w2T   = (short*)alloc((size_t)2*1024*4096*2);
  float* x     = (float*)alloc((size_t)4096*1024*4);
  short* hbuf  = (short*)alloc((size_t)4096*1024*2);
  short* qkv   = (short*)alloc((size_t)4096*3072*2);
  short* qr    = (short*)alloc((size_t)4096*1024*2);
  short* kr    = (short*)alloc((size_t)4096*1024*2);
  short* vt    = (short*)alloc((size_t)4096*1024*2);
  short* obuf  = (short*)alloc((size_t)4096*1024*2);
  short* mbuf  = (short*)alloc((size_t)4096*4096*2);
  float* psum  = (float*)alloc((size_t)4*4096*1024*4);

  for (int l = 0; l < 2; ++l){
    size_t wOff = (size_t)l*1024*1024;
    wtrans_kernel<<<dim3(16,16),256,0,stream>>>(wq + wOff, wqkvT + (size_t)l*3072*1024,                     1024, 1024);
    wtrans_kernel<<<dim3(16,16),256,0,stream>>>(wk + wOff, wqkvT + (size_t)l*3072*1024 + (size_t)1024*1024, 1024, 1024);
    wtrans_kernel<<<dim3(16,16),256,0,stream>>>(wv + wOff, wqkvT + (size_t)l*3072*1024 + (size_t)2048*1024, 1024, 1024);
    wtrans_kernel<<<dim3(16,16),256,0,stream>>>(wo + wOff, woT + (size_t)l*1024*1024,                       1024, 1024);
    wtrans_inter_kernel<<<dim3(64,16),256,0,stream>>>(w1 + (size_t)l*1024*4096, w13T + (size_t)l*8192*1024, 1024, 4096, 0);
    wtrans_inter_kernel<<<dim3(64,16),256,0,stream>>>(w3 + (size_t)l*1024*4096, w13T + (size_t)l*8192*1024, 1024, 4096, 16);
    wtrans_kernel<<<dim3(16,64),256,0,stream>>>(w2 + (size_t)l*4096*1024, w2T + (size_t)l*1024*4096,        4096, 1024);
  }
  gather_kernel<<<dim3(2048,2),256,0,stream>>>(x_processed, boundaries, x_residual, x);
  for (int l = 0; l < 2; ++l){
    rmsnorm_kernel<1><<<4096,256,0,stream>>>(x, attn_nw + l*1024, hbuf);
    gemm8p<0><<<12*16,512,0,stream>>>(hbuf, wqkvT + (size_t)l*3072*1024, qkv, 4096, 3072, 1024, 12, 16);
    rope_kernel<<<8192,256,0,stream>>>(qkv, cosb, sinb, qr, kr);
    vtrans_kernel<<<dim3(32,32),256,0,stream>>>(qkv, vt);
    attn_kernel<<<dim3(16,16,2),256,0,stream>>>(qr, kr, vt, obuf);
    gemm_bt<1><<<8*32,256,0,stream>>>(obuf, woT + (size_t)l*1024*1024, x, 4096, 1024, 1024, 8, 32);
    rmsnorm_kernel<1><<<4096,256,0,stream>>>(x, mlp_nw + l*1024, hbuf);
    gemm8p<1><<<32*16,512,0,stream>>>(hbuf, w13T + (size_t)l*8192*1024, mbuf, 4096, 8192, 1024, 32, 16);
    gemm_splitk<<<8*32*4,256,0,stream>>>(mbuf, w2T + (size_t)l*1024*4096, psum, 4096, 1024, 4096, 1024, 8, 32);
    redadd_kernel<<<4096,256,0,stream>>>(x, psum);
  }
  rmsnorm_kernel<0><<<4096,256,0,stream>>>(x, final_nw, d_out);
}

// Round 7
// 618.062 us; speedup vs baseline: 1.7766x; 1.0458x over previous
//
#include <hip/hip_runtime.h>
#include <stdint.h>

typedef __attribute__((ext_vector_type(8))) short s16x8;
typedef __attribute__((ext_vector_type(4))) float f32x4;

#define CB 2
#define CT 2048
#define CD 1024
#define CNH 16
#define CHD 64
#define CDFF 4096
#define CKB 512

__device__ __forceinline__ short f2bf(float f){
  union { float f; uint32_t u; } v; v.f = f;
  uint32_t r = v.u + 0x7FFFu + ((v.u >> 16) & 1u);
  return (short)(r >> 16);
}
__device__ __forceinline__ float bf2f(short h){
  union { uint32_t u; float f; } v; v.u = ((uint32_t)(uint16_t)h) << 16;
  return v.f;
}
__device__ __forceinline__ uint32_t cvtpk_bf16(float lo, float hi){
  uint32_t r;
  asm("v_cvt_pk_bf16_f32 %0, %1, %2" : "=v"(r) : "v"(lo), "v"(hi));
  return r;
}

#define GLOAD16(g, l) __builtin_amdgcn_global_load_lds( \
    (const __attribute__((address_space(1))) void*)(g), \
    (__attribute__((address_space(3))) void*)(l), 16, 0, 0)

// ---------------- gather + residual ----------------
__global__ void gather_kernel(const float* __restrict__ xp, const int* __restrict__ bnd,
                              const float* __restrict__ xr, float* __restrict__ x){
  int t = blockIdx.x, b = blockIdx.y, tid = threadIdx.x;
  int lo = 0, hi = CKB;
  while (lo < hi){ int mid = (lo + hi) >> 1; if (bnd[b*CKB + mid] <= t) lo = mid + 1; else hi = mid; }
  const float4* s  = (const float4*)(xp + ((size_t)b*CKB + lo)*CD);
  const float4* rr = (const float4*)(xr + ((size_t)b*CT + t)*CD);
  float4* dst      = (float4*)(x  + ((size_t)b*CT + t)*CD);
  float4 a = s[tid], c = rr[tid];
  float4 o; o.x = a.x + c.x; o.y = a.y + c.y; o.z = a.z + c.z; o.w = a.w + c.w;
  dst[tid] = o;
}

// ---------------- weight fp32 -> bf16 transpose ----------------
__global__ void wtrans_kernel(const float* __restrict__ W, short* __restrict__ dst,
                              int Kd, int Nd){
  __shared__ __align__(16) float tile[64*65];
  int n0 = blockIdx.x*64, k0 = blockIdx.y*64;
  #pragma unroll
  for (int i = 0; i < 16; ++i){
    int e = threadIdx.x + 256*i; int kl = e >> 6, nl = e & 63;
    tile[kl*65 + nl] = W[(size_t)(k0 + kl)*Nd + n0 + nl];
  }
  __syncthreads();
  #pragma unroll
  for (int i = 0; i < 16; ++i){
    int e = threadIdx.x + 256*i; int nl = e >> 6, kl = e & 63;
    dst[(size_t)(n0 + nl)*Kd + k0 + kl] = f2bf(tile[kl*65 + nl]);
  }
}

// interleaved variant for w1/w3: dst row = (c/16)*32 + off16 + c%16
__global__ void wtrans_inter_kernel(const float* __restrict__ W, short* __restrict__ dst,
                                    int Kd, int Nd, int off16){
  __shared__ __align__(16) float tile[64*65];
  int n0 = blockIdx.x*64, k0 = blockIdx.y*64;
  #pragma unroll
  for (int i = 0; i < 16; ++i){
    int e = threadIdx.x + 256*i; int kl = e >> 6, nl = e & 63;
    tile[kl*65 + nl] = W[(size_t)(k0 + kl)*Nd + n0 + nl];
  }
  __syncthreads();
  #pragma unroll
  for (int i = 0; i < 16; ++i){
    int e = threadIdx.x + 256*i; int nl = e >> 6, kl = e & 63;
    int c = n0 + nl;
    int frow = ((c >> 4) << 5) + off16 + (c & 15);
    dst[(size_t)frow*Kd + k0 + kl] = f2bf(tile[kl*65 + nl]);
  }
}

// ---------------- RMSNorm ----------------
template<int OUT_BF16>
__global__ void rmsnorm_kernel(const float* __restrict__ x, const float* __restrict__ w,
                               void* __restrict__ outv){
  int row = blockIdx.x, tid = threadIdx.x;
  const float4 xv = ((const float4*)(x + (size_t)row*CD))[tid];
  float ss = xv.x*xv.x + xv.y*xv.y + xv.z*xv.z + xv.w*xv.w;
  #pragma unroll
  for (int m = 1; m < 64; m <<= 1) ss += __shfl_xor(ss, m);
  __shared__ float red[4];
  if ((tid & 63) == 0) red[tid >> 6] = ss;
  __syncthreads();
  float tot = red[0] + red[1] + red[2] + red[3];
  float scale = rsqrtf(tot * (1.0f/1024.0f) + 1e-5f);
  const float4 wv = ((const float4*)w)[tid];
  if (OUT_BF16){
    short4 o;
    o.x = f2bf(xv.x*scale*wv.x); o.y = f2bf(xv.y*scale*wv.y);
    o.z = f2bf(xv.z*scale*wv.z); o.w = f2bf(xv.w*scale*wv.w);
    ((short4*)outv)[(size_t)row*256 + tid] = o;
  } else {
    float4 o;
    o.x = xv.x*scale*wv.x; o.y = xv.y*scale*wv.y;
    o.z = xv.z*scale*wv.z; o.w = xv.w*scale*wv.w;
    ((float4*)outv)[(size_t)row*256 + tid] = o;
  }
}

// ---------------- fused x += sum(psum[0..3]) then RMSNorm ----------------
template<int OUT_BF16>
__global__ void redrms_kernel(float* __restrict__ x, const float* __restrict__ Cp,
                              const float* __restrict__ w, void* __restrict__ outv){
  int row = blockIdx.x, tid = threadIdx.x;
  size_t i = (size_t)row*256 + tid;
  const float4* p0 = (const float4*)Cp;
  const float4* p1 = p0 + (size_t)1048576;
  const float4* p2 = p1 + (size_t)1048576;
  const float4* p3 = p2 + (size_t)1048576;
  float4 a = ((float4*)x)[i];
  float4 q0 = p0[i], q1 = p1[i], q2 = p2[i], q3 = p3[i];
  a.x += (q0.x + q1.x) + (q2.x + q3.x);
  a.y += (q0.y + q1.y) + (q2.y + q3.y);
  a.z += (q0.z + q1.z) + (q2.z + q3.z);
  a.w += (q0.w + q1.w) + (q2.w + q3.w);
  if (OUT_BF16) ((float4*)x)[i] = a;   // residual stream continues only mid-net
  float ss = a.x*a.x + a.y*a.y + a.z*a.z + a.w*a.w;
  #pragma unroll
  for (int m = 1; m < 64; m <<= 1) ss += __shfl_xor(ss, m);
  __shared__ float red[4];
  if ((tid & 63) == 0) red[tid >> 6] = ss;
  __syncthreads();
  float tot = red[0] + red[1] + red[2] + red[3];
  float scale = rsqrtf(tot * (1.0f/1024.0f) + 1e-5f);
  const float4 wv = ((const float4*)w)[tid];
  if (OUT_BF16){
    short4 o;
    o.x = f2bf(a.x*scale*wv.x); o.y = f2bf(a.y*scale*wv.y);
    o.z = f2bf(a.z*scale*wv.z); o.w = f2bf(a.w*scale*wv.w);
    ((short4*)outv)[(size_t)row*256 + tid] = o;
  } else {
    float4 o;
    o.x = a.x*scale*wv.x; o.y = a.y*scale*wv.y;
    o.z = a.z*scale*wv.z; o.w = a.w*scale*wv.w;
    ((float4*)outv)[(size_t)row*256 + tid] = o;
  }
}

// ---------------- block-index swizzle (m204 bijective XCD + GM raster) ----------
__device__ __forceinline__ void swz_block_id(int id, int NX, int NY, int& bm, int& bn){
  const int nwg = NX*NY;
  const int qq = nwg >> 3, rr8 = nwg & 7;
  const int xcd = id & 7, loc = id >> 3;
  const int wgid = (xcd < rr8 ? xcd*(qq+1) : rr8*(qq+1) + (xcd-rr8)*qq) + loc;
  const int GM = 8;
  const int gsz = GM * NX;
  const int gidg = wgid / gsz;
  const int remg = wgid - gidg*gsz;
  bm = gidg*GM + (remg % GM);
  bn = remg / GM;
}

// ---------------- GEMM 2-phase 128x128 (WO) ----------------
template<int EPI>
__global__ __launch_bounds__(256) void gemm_bt(const short* __restrict__ A,
                                               const short* __restrict__ Bt,
                                               void* __restrict__ Cv,
                                               int M, int N, int K,
                                               int NX, int NY){
  __shared__ __align__(16) short sA[2][128*32];
  __shared__ __align__(16) short sB[2][128*32];
  const int tid = threadIdx.x;
  const int lane = tid & 63, wid = tid >> 6;
  const int wm = wid >> 1, wn = wid & 1;
  const int lr = lane & 15, lg = lane >> 4;
  int bm, bn; swz_block_id(blockIdx.x, NX, NY, bm, bn);
  const int bm0 = bm * 128, bn0 = bn * 128;

  f32x4 acc[4][4];
  #pragma unroll
  for (int i = 0; i < 4; ++i)
    #pragma unroll
    for (int j = 0; j < 4; ++j) acc[i][j] = (f32x4){0.f,0.f,0.f,0.f};

  const short* gA = A  + (size_t)(bm0 + wid*32 + (lane >> 2))*K + (lane & 3)*8;
  const short* gB = Bt + (size_t)(bn0 + wid*32 + (lane >> 2))*K + (lane & 3)*8;

  #pragma unroll
  for (int iss = 0; iss < 2; ++iss){
    GLOAD16(gA + (size_t)iss*16*K, &sA[0][wid*1024 + iss*16*32]);
    GLOAD16(gB + (size_t)iss*16*K, &sB[0][wid*1024 + iss*16*32]);
  }
  __syncthreads();

  int cur = 0;
  for (int k0 = 0; k0 < K; k0 += 32){
    if (k0 + 32 < K){
      #pragma unroll
      for (int iss = 0; iss < 2; ++iss){
        GLOAD16(gA + (size_t)iss*16*K + k0 + 32, &sA[cur^1][wid*1024 + iss*16*32]);
        GLOAD16(gB + (size_t)iss*16*K + k0 + 32, &sB[cur^1][wid*1024 + iss*16*32]);
      }
    }
    s16x8 af[4], bq[4];
    #pragma unroll
    for (int i = 0; i < 4; ++i) af[i] = *(const s16x8*)&sA[cur][(wm*64 + i*16 + lr)*32 + lg*8];
    #pragma unroll
    for (int j = 0; j < 4; ++j) bq[j] = *(const s16x8*)&sB[cur][(wn*64 + j*16 + lr)*32 + lg*8];
    #pragma unroll
    for (int i = 0; i < 4; ++i)
      #pragma unroll
      for (int j = 0; j < 4; ++j)
        acc[i][j] = __builtin_amdgcn_mfma_f32_16x16x32_bf16(af[i], bq[j], acc[i][j], 0, 0, 0);
    __syncthreads();
    cur ^= 1;
  }

  if (EPI == 0){
    short* C = (short*)Cv;
    #pragma unroll
    for (int i = 0; i < 4; ++i){
      int row0 = bm0 + wm*64 + i*16 + lg*4;
      #pragma unroll
      for (int j = 0; j < 4; ++j){
        int col = bn0 + wn*64 + j*16 + lr;
        #pragma unroll
        for (int r = 0; r < 4; ++r) C[(size_t)(row0 + r)*N + col] = f2bf(acc[i][j][r]);
      }
    }
  } else {
    float* C = (float*)Cv;
    #pragma unroll
    for (int i = 0; i < 4; ++i){
      int row0 = bm0 + wm*64 + i*16 + lg*4;
      #pragma unroll
      for (int j = 0; j < 4; ++j){
        int col = bn0 + wn*64 + j*16 + lr;
        #pragma unroll
        for (int r = 0; r < 4; ++r) C[(size_t)(row0 + r)*N + col] += acc[i][j][r];
      }
    }
  }
}

// ---------------- GEMM pair-phase 256x256, BK=64, 8 waves, counted vmcnt -------
// LDS: 2 buf x 4 units (A-kh0,B-kh0,A-kh1,B-kh1) x [256][32] bf16 = 128 KiB.
// Per K-tile: 2 pair-phases, each {stage 2 half-tiles | 12 ds_read_b128 |
// barrier | lgkmcnt(0) | 32 MFMA | vmcnt(4) | barrier}. B-frags read once.
#define STAGE8(u, kt, bufx) do { \
  const short* Gp_ = ((u)&1) ? Bt : A; \
  const int rb_ = ((u)&1) ? bn0 : bm0; \
  const int kh_ = (u)>>1; \
  _Pragma("unroll") \
  for (int L_ = 0; L_ < 2; ++L_){ \
    int rowS_ = L_*128 + wid*16 + (lane>>2); \
    int sp_ = (lane&3) ^ ((rowS_>>1)&3); \
    GLOAD16(Gp_ + (size_t)(rb_ + rowS_)*Kstr + (size_t)(kt)*64 + kh_*32 + sp_*8, \
            &sAB[bufx][u][(L_*512 + wid*64)*8]); \
  } \
} while(0)

#define LDSRD(bufx, u, rowv) \
  (*(const s16x8*)&sAB[bufx][u][(rowv)*32 + (((lg) ^ (((rowv)>>1)&3))<<3)])

#define PHASEPAIR(kk) do { \
  if (pf){ STAGE8(2*(kk), kt+1, nbuf); STAGE8(2*(kk)+1, kt+1, nbuf); } \
  s16x8 af0_[4], af1_[4], bq_[4]; \
  _Pragma("unroll") \
  for (int j_ = 0; j_ < 4; ++j_) bq_[j_] = LDSRD(buf, (kk)*2+1, wn*64 + j_*16 + lr); \
  _Pragma("unroll") \
  for (int i_ = 0; i_ < 4; ++i_) af0_[i_] = LDSRD(buf, (kk)*2, wm*128 + i_*16 + lr); \
  _Pragma("unroll") \
  for (int i_ = 0; i_ < 4; ++i_) af1_[i_] = LDSRD(buf, (kk)*2, wm*128 + 64 + i_*16 + lr); \
  __builtin_amdgcn_s_barrier(); \
  asm volatile("s_waitcnt lgkmcnt(0)" ::: "memory"); \
  __builtin_amdgcn_s_setprio(1); \
  _Pragma("unroll") \
  for (int i_ = 0; i_ < 4; ++i_) \
    _Pragma("unroll") \
    for (int j_ = 0; j_ < 4; ++j_) \
      acc[i_][j_] = __builtin_amdgcn_mfma_f32_16x16x32_bf16(af0_[i_], bq_[j_], acc[i_][j_], 0, 0, 0); \
  _Pragma("unroll") \
  for (int i_ = 0; i_ < 4; ++i_) \
    _Pragma("unroll") \
    for (int j_ = 0; j_ < 4; ++j_) \
      acc[4+i_][j_] = __builtin_amdgcn_mfma_f32_16x16x32_bf16(af1_[i_], bq_[j_], acc[4+i_][j_], 0, 0, 0); \
  __builtin_amdgcn_s_setprio(0); \
  if (pf) asm volatile("s_waitcnt vmcnt(4)" ::: "memory"); \
  else if ((kk) == 0) asm volatile("s_waitcnt vmcnt(0)" ::: "memory"); \
  __builtin_amdgcn_s_barrier(); \
} while(0)

// FUSE 0: bf16 C[M,N].  FUSE 1: silu-fused interleaved -> bf16 C[M,N/2].
// FUSE 2: fp32 partial C[M,N] at Cp + split*M*N (split-K).
template<int FUSE>
__global__ __launch_bounds__(512, 2) void gemm8p(const short* __restrict__ A,
                                                 const short* __restrict__ Bt,
                                                 void* __restrict__ Cv,
                                                 int M, int N, int Kstr, int Kchunk,
                                                 int NX, int NY){
  __shared__ __align__(16) short sAB[2][4][256*32];
  const int tid = threadIdx.x;
  const int lane = tid & 63, wid = tid >> 6;
  const int wm = wid >> 2, wn = wid & 3;
  const int lr = lane & 15, lg = lane >> 4;
  const int nin = NX*NY;
  const int split = blockIdx.x / nin;
  const int inner = blockIdx.x - split*nin;
  int bm, bn; swz_block_id(inner, NX, NY, bm, bn);
  const int bm0 = bm * 256, bn0 = bn * 256;
  A  += (size_t)split * Kchunk;
  Bt += (size_t)split * Kchunk;

  f32x4 acc[8][4];
  #pragma unroll
  for (int i = 0; i < 8; ++i)
    #pragma unroll
    for (int j = 0; j < 4; ++j) acc[i][j] = (f32x4){0.f,0.f,0.f,0.f};

  const int NK = Kchunk >> 6;
  STAGE8(0, 0, 0);
  STAGE8(1, 0, 0);
  STAGE8(2, 0, 0);
  STAGE8(3, 0, 0);
  asm volatile("s_waitcnt vmcnt(4)" ::: "memory");
  __builtin_amdgcn_s_barrier();

  #pragma unroll 1
  for (int kt = 0; kt < NK; ++kt){
    const bool pf = (kt + 1 < NK);
    const int buf = kt & 1, nbuf = buf ^ 1;
    PHASEPAIR(0);
    PHASEPAIR(1);
  }

  if (FUSE == 0){
    short* C = (short*)Cv;
    #pragma unroll
    for (int i = 0; i < 8; ++i){
      int row0 = bm0 + wm*128 + i*16 + lg*4;
      #pragma unroll
      for (int j = 0; j < 4; ++j){
        int col = bn0 + wn*64 + j*16 + lr;
        #pragma unroll
        for (int r = 0; r < 4; ++r) C[(size_t)(row0 + r)*N + col] = f2bf(acc[i][j][r]);
      }
    }
  } else if (FUSE == 1){
    short* C = (short*)Cv;
    const int Nh = N >> 1;
    #pragma unroll
    for (int i = 0; i < 8; ++i){
      int row0 = bm0 + wm*128 + i*16 + lg*4;
      #pragma unroll
      for (int jp = 0; jp < 2; ++jp){
        int col = (bn0 >> 1) + wn*32 + jp*16 + lr;
        #pragma unroll
        for (int r = 0; r < 4; ++r){
          float u = acc[i][jp*2][r], g = acc[i][jp*2+1][r];
          float val = u / (1.f + __expf(-u)) * g;
          C[(size_t)(row0 + r)*Nh + col] = f2bf(val);
        }
      }
    }
  } else {
    float* C = (float*)Cv + (size_t)split*M*N;
    #pragma unroll
    for (int i = 0; i < 8; ++i){
      int row0 = bm0 + wm*128 + i*16 + lg*4;
      #pragma unroll
      for (int j = 0; j < 4; ++j){
        int col = bn0 + wn*64 + j*16 + lr;
        #pragma unroll
        for (int r = 0; r < 4; ++r) C[(size_t)(row0 + r)*N + col] = acc[i][j][r];
      }
    }
  }
}

// ---------------- RoPE (q scaled by 0.125*log2e for exp2-domain softmax) -------
__global__ void rope_kernel(const short* __restrict__ qkv, const float* __restrict__ cosb,
                            const float* __restrict__ sinb, short* __restrict__ Qo,
                            short* __restrict__ Ko){
  int g = blockIdx.x*256 + threadIdx.x;
  int d = g & 31;
  int h = (g >> 5) & 15;
  int t = (g >> 9) & 2047;
  int b = g >> 20;
  size_t row = (size_t)b*CT + t;
  const short* src = qkv + row*3072 + h*64;
  float q0 = bf2f(src[d]),        q1 = bf2f(src[d+32]);
  float k0 = bf2f(src[1024+d]),   k1 = bf2f(src[1024+d+32]);
  float c0 = cosb[t*64 + d], c1 = cosb[t*64 + d + 32];
  float s0 = sinb[t*64 + d], s1 = sinb[t*64 + d + 32];
  size_t o = row*CD + h*64;
  const float sc = 0.125f * 1.44269504088896340736f;
  Qo[o + d]      = f2bf((q0*c0 - q1*s0)*sc);
  Qo[o + d + 32] = f2bf((q1*c1 + q0*s1)*sc);
  Ko[o + d]      = f2bf(k0*c0 - k1*s0);
  Ko[o + d + 32] = f2bf(k1*c1 + k0*s1);
}

// ---------------- V transpose ----------------
__global__ void vtrans_kernel(const short* __restrict__ qkv, short* __restrict__ Vt){
  __shared__ __align__(16) short tile[64*65];
  int t0 = blockIdx.x*64;
  int h = blockIdx.y & 15, b = blockIdx.y >> 4;
  #pragma unroll
  for (int i = 0; i < 16; ++i){
    int e = threadIdx.x + 256*i; int tl = e >> 6, d = e & 63;
    tile[tl*65 + d] = qkv[(size_t)(b*CT + t0 + tl)*3072 + 2048 + h*64 + d];
  }
  __syncthreads();
  #pragma unroll
  for (int i = 0; i < 16; ++i){
    int e = threadIdx.x + 256*i; int dl = e >> 6, tl = e & 63;
    Vt[((size_t)(b*CNH + h)*CHD + dl)*CT + t0 + tl] = tile[tl*65 + dl];
  }
}

// ---------------- causal flash attention v3 ----------------
__global__ __launch_bounds__(256) void attn_kernel(const short* __restrict__ Q,
                                                   const short* __restrict__ Kb,
                                                   const short* __restrict__ Vt,
                                                   short* __restrict__ O){
  __shared__ __align__(16) short Kl[2][64*72];
  __shared__ __align__(16) short Vl[2][64*72];
  __shared__ __align__(16) short Pl[4][16*72];
  const int tid = threadIdx.x, lane = tid & 63, w = tid >> 6;
  const int qpair = blockIdx.x;          // 0..15
  const int h = blockIdx.y, b = blockIdx.z;
  const int lr = lane & 15, lg = lane >> 4;

  const short* gK = Kb + (size_t)b*CT*CD + h*CHD;
  const short* gV = Vt + (size_t)(b*CNH + h)*CHD*CT;
  const int srow0 = tid >> 3, scol = (tid & 7)*8;

  #pragma unroll 1
  for (int half = 0; half < 2; ++half){
    const int qt = half ? qpair : (31 - qpair);
    const int wq0 = qt*64 + w*16;
    const int jmax = qt + 1;

    s16x8 qf0, qf1;
    {
      const short* qp = Q + ((size_t)(b*CT + wq0 + lr)*CNH + h)*CHD + lg*8;
      qf0 = *(const s16x8*)qp;
      qf1 = *(const s16x8*)(qp + 32);
    }
    f32x4 oacc[4];
    #pragma unroll
    for (int dt = 0; dt < 4; ++dt) oacc[dt] = (f32x4){0.f,0.f,0.f,0.f};
    float m_r = -1e30f, l_r = 0.f;

    #pragma unroll
    for (int p = 0; p < 2; ++p){
      int row = srow0 + p*32;
      *(s16x8*)&Kl[0][row*72 + scol] = *(const s16x8*)(gK + (size_t)row*CD + scol);
      *(s16x8*)&Vl[0][row*72 + scol] = *(const s16x8*)(gV + (size_t)row*CT + scol);
    }
    __syncthreads();

    #pragma unroll 1
    for (int j = 0; j < jmax; ++j){
      const int kv0 = j*64;
      const int buf = j & 1;
      s16x8 nk[2], nv[2];
      const bool havenext = (j + 1 < jmax);
      if (havenext){
        const int kv1 = kv0 + 64;
        #pragma unroll
        for (int p = 0; p < 2; ++p){
          int row = srow0 + p*32;
          nk[p] = *(const s16x8*)(gK + (size_t)(kv1 + row)*CD + scol);
          nv[p] = *(const s16x8*)(gV + (size_t)row*CT + kv1 + scol);
        }
      }

      if (kv0 < wq0 + 16){
        f32x4 sc[4];
        __builtin_amdgcn_s_setprio(1);
        #pragma unroll
        for (int nt = 0; nt < 4; ++nt){
          s16x8 k0 = *(const s16x8*)&Kl[buf][(nt*16 + lr)*72 + lg*8];
          s16x8 k1 = *(const s16x8*)&Kl[buf][(nt*16 + lr)*72 + 32 + lg*8];
          f32x4 z = (f32x4){0.f,0.f,0.f,0.f};
          z = __builtin_amdgcn_mfma_f32_16x16x32_bf16(k0, qf0, z, 0, 0, 0);
          z = __builtin_amdgcn_mfma_f32_16x16x32_bf16(k1, qf1, z, 0, 0, 0);
          sc[nt] = z;
        }
        __builtin_amdgcn_s_setprio(0);
        if (kv0 + 64 > wq0){
          #pragma unroll
          for (int nt = 0; nt < 4; ++nt)
            #pragma unroll
            for (int r = 0; r < 4; ++r)
              if (kv0 + nt*16 + lg*4 + r > wq0 + lr) sc[nt][r] = -1e30f;
        }
        float pmax = sc[0][0];
        #pragma unroll
        for (int nt = 0; nt < 4; ++nt)
          #pragma unroll
          for (int r = 0; r < 4; ++r) pmax = fmaxf(pmax, sc[nt][r]);
        pmax = fmaxf(pmax, __shfl_xor(pmax, 16));
        pmax = fmaxf(pmax, __shfl_xor(pmax, 32));
        if (!__all(pmax - m_r <= 10.f)){
          float mn = fmaxf(m_r, pmax);
          float corr = __builtin_amdgcn_exp2f(m_r - mn);
          m_r = mn;
          l_r *= corr;
          #pragma unroll
          for (int r = 0; r < 4; ++r){
            float c4 = __shfl(corr, lg*4 + r);
            #pragma unroll
            for (int dt = 0; dt < 4; ++dt) oacc[dt][r] *= c4;
          }
        }
        float rs = 0.f;
        #pragma unroll
        for (int nt = 0; nt < 4; ++nt)
          #pragma unroll
          for (int r = 0; r < 4; ++r){
            float pv = __builtin_amdgcn_exp2f(sc[nt][r] - m_r);
            sc[nt][r] = pv;
            rs += pv;
          }
        #pragma unroll
        for (int nt = 0; nt < 4; ++nt){
          uint2 pk;
          pk.x = cvtpk_bf16(sc[nt][0], sc[nt][1]);
          pk.y = cvtpk_bf16(sc[nt][2], sc[nt][3]);
          *(uint2*)&Pl[w][lr*72 + nt*16 + lg*4] = pk;
        }
        rs += __shfl_xor(rs, 16);
        rs += __shfl_xor(rs, 32);
        l_r += rs;
        s16x8 pa0 = *(const s16x8*)&Pl[w][lr*72 + lg*8];
        s16x8 pa1 = *(const s16x8*)&Pl[w][lr*72 + 32 + lg*8];
        __builtin_amdgcn_s_setprio(1);
        #pragma unroll
        for (int dt = 0; dt < 4; ++dt){
          s16x8 v0 = *(const s16x8*)&Vl[buf][(dt*16 + lr)*72 + lg*8];
          s16x8 v1 = *(const s16x8*)&Vl[buf][(dt*16 + lr)*72 + 32 + lg*8];
          oacc[dt] = __builtin_amdgcn_mfma_f32_16x16x32_bf16(pa0, v0, oacc[dt], 0, 0, 0);
          oacc[dt] = __builtin_amdgcn_mfma_f32_16x16x32_bf16(pa1, v1, oacc[dt], 0, 0, 0);
        }
        __builtin_amdgcn_s_setprio(0);
      }
      if (havenext){
        #pragma unroll
        for (int p = 0; p < 2; ++p){
          int row = srow0 + p*32;
          *(s16x8*)&Kl[buf^1][row*72 + scol] = nk[p];
          *(s16x8*)&Vl[buf^1][row*72 + scol] = nv[p];
        }
      }
      __syncthreads();
    }

    #pragma unroll
    for (int r = 0; r < 4; ++r){
      float lf = __shfl(l_r, lg*4 + r);
      float inv = 1.f / lf;
      int qrow = wq0 + lg*4 + r;
      #pragma unroll
      for (int dt = 0; dt < 4; ++dt)
        O[((size_t)(b*CT + qrow)*CNH + h)*CHD + dt*16 + lr] = f2bf(oacc[dt][r] * inv);
    }
  }
}

// ---------------- launch ----------------
extern "C" void kernel_launch(void* const* d_in, const int* in_sizes, int n_in,
                              void* d_out, int out_size, void* d_ws, size_t ws_size,
                              hipStream_t stream){
  (void)in_sizes; (void)n_in; (void)out_size; (void)ws_size;
  const float* x_processed = (const float*)d_in[0];
  const int*   boundaries  = (const int*)d_in[1];
  const float* x_residual  = (const float*)d_in[3];
  const float* cosb        = (const float*)d_in[4];
  const float* sinb        = (const float*)d_in[5];
  const float* wq          = (const float*)d_in[7];
  const float* wk          = (const float*)d_in[8];
  const float* wv          = (const float*)d_in[9];
  const float* wo          = (const float*)d_in[10];
  const float* attn_nw     = (const float*)d_in[11];
  const float* mlp_nw      = (const float*)d_in[12];
  const float* w1          = (const float*)d_in[13];
  const float* w3          = (const float*)d_in[14];
  const float* w2          = (const float*)d_in[15];
  const float* final_nw    = (const float*)d_in[16];

  char* p = (char*)d_ws;
  auto alloc = [&](size_t bytes)->char*{
    char* r = p; p += (bytes + 255) & ~(size_t)255; return r;
  };
  short* wqkvT = (short*)alloc((size_t)2*3072*1024*2);
  short* woT   = (short*)alloc((size_t)2*1024*1024*2);
  short* w13T  = (short*)alloc((size_t)2*8192*1024*2);
  short* w2T   = (short*)alloc((size_t)2*1024*4096*2);
  float* x     = (float*)alloc((size_t)4096*1024*4);
  short* hbuf  = (short*)alloc((size_t)4096*1024*2);
  short* qkv   = (short*)alloc((size_t)4096*3072*2);
  short* qr    = (short*)alloc((size_t)4096*1024*2);
  short* kr    = (short*)alloc((size_t)4096*1024*2);
  short* vt    = (short*)alloc((size_t)4096*1024*2);
  short* obuf  = (short*)alloc((size_t)4096*1024*2);
  short* mbuf  = (short*)alloc((size_t)4096*4096*2);
  float* psum  = (float*)alloc((size_t)4*4096*1024*4);

  for (int l = 0; l < 2; ++l){
    size_t wOff = (size_t)l*1024*1024;
    wtrans_kernel<<<dim3(16,16),256,0,stream>>>(wq + wOff, wqkvT + (size_t)l*3072*1024,                     1024, 1024);
    wtrans_kernel<<<dim3(16,16),256,0,stream>>>(wk + wOff, wqkvT + (size_t)l*3072*1024 + (size_t)1024*1024, 1024, 1024);
    wtrans_kernel<<<dim3(16,16),256,0,stream>>>(wv + wOff, wqkvT + (size_t)l*3072*1024 + (size_t)2048*1024, 1024, 1024);
    wtrans_kernel<<<dim3(16,16),256,0,stream>>>(wo + wOff, woT + (size_t)l*1024*1024,                       1024, 1024);
    wtrans_inter_kernel<<<dim3(64,16),256,0,stream>>>(w1 + (size_t)l*1024*4096, w13T + (size_t)l*8192*1024, 1024, 4096, 0);
    wtrans_inter_kernel<<<dim3(64,16),256,0,stream>>>(w3 + (size_t)l*1024*4096, w13T + (size_t)l*8192*1024, 1024, 4096, 16);
    wtrans_kernel<<<dim3(16,64),256,0,stream>>>(w2 + (size_t)l*4096*1024, w2T + (size_t)l*1024*4096,        4096, 1024);
  }
  gather_kernel<<<dim3(2048,2),256,0,stream>>>(x_processed, boundaries, x_residual, x);
  rmsnorm_kernel<1><<<4096,256,0,stream>>>(x, attn_nw, hbuf);
  for (int l = 0; l < 2; ++l){
    gemm8p<0><<<12*16,512,0,stream>>>(hbuf, wqkvT + (size_t)l*3072*1024, qkv, 4096, 3072, 1024, 1024, 12, 16);
    rope_kernel<<<8192,256,0,stream>>>(qkv, cosb, sinb, qr, kr);
    vtrans_kernel<<<dim3(32,32),256,0,stream>>>(qkv, vt);
    attn_kernel<<<dim3(16,16,2),256,0,stream>>>(qr, kr, vt, obuf);
    gemm_bt<1><<<8*32,256,0,stream>>>(obuf, woT + (size_t)l*1024*1024, x, 4096, 1024, 1024, 8, 32);
    rmsnorm_kernel<1><<<4096,256,0,stream>>>(x, mlp_nw + l*1024, hbuf);
    gemm8p<1><<<32*16,512,0,stream>>>(hbuf, w13T + (size_t)l*8192*1024, mbuf, 4096, 8192, 1024, 1024, 32, 16);
    gemm8p<2><<<4*4*16,512,0,stream>>>(mbuf, w2T + (size_t)l*1024*4096, psum, 4096, 1024, 4096, 1024, 4, 16);
    if (l == 0) redrms_kernel<1><<<4096,256,0,stream>>>(x, psum, attn_nw + 1024, hbuf);
    else        redrms_kernel<0><<<4096,256,0,stream>>>(x, psum, final_nw, d_out);
  }
}